// Round 1
// baseline (927.022 us; speedup 1.0000x reference)
//
#include <hip/hip_runtime.h>
#include <math.h>

// Problem constants (asserted against in_sizes in kernel_launch):
//   N=50000 nodes, E=800000 edges, F_IN=128, H=128, C=16. All f32; edges int32.

// ---------------- degree ----------------
__global__ void deg_kernel(const int* __restrict__ dst, float* __restrict__ deg, int E) {
    int i = blockIdx.x * blockDim.x + threadIdx.x;
    if (i < E) atomicAdd(&deg[dst[i]], 1.0f);
}

__global__ void dinv_kernel(float* __restrict__ deg_dinv, int N) {
    int i = blockIdx.x * blockDim.x + threadIdx.x;
    if (i < N) deg_dinv[i] = rsqrtf(deg_dinv[i] + 1.0f);  // +1 for self-loop; always >=1
}

// ---------------- gemm1: h1[N,128] = x[N,128] @ W1[128,128] ----------------
// 64 rows/block, 256 threads, k staged in 2 chunks of 64. LDS = 16KB(x) + 32KB(W) = 48KB.
__global__ __launch_bounds__(256)
void gemm1_kernel(const float* __restrict__ x, const float* __restrict__ W,
                  float* __restrict__ h, int N) {
    __shared__ float xs[64 * 64];     // [row][k]
    __shared__ float wsh[64 * 128];   // [k][col]
    const int tid = threadIdx.x;
    const int row0 = blockIdx.x * 64;
    const int ty = tid >> 5;          // 0..7 -> 8 rows each
    const int tx = tid & 31;          // 0..31 -> 4 cols each

    float acc[8][4];
#pragma unroll
    for (int r = 0; r < 8; r++)
#pragma unroll
        for (int c = 0; c < 4; c++) acc[r][c] = 0.0f;

    for (int kk = 0; kk < 128; kk += 64) {
        // stage x tile: 64 rows x 64 k = 1024 float4
        const float4* xg = (const float4*)x;
        for (int i = tid; i < 1024; i += 256) {
            int r = i >> 4, k4 = i & 15;
            int row = row0 + r;
            float4 v = make_float4(0.f, 0.f, 0.f, 0.f);
            if (row < N) v = xg[row * 32 + (kk >> 2) + k4];
            ((float4*)xs)[i] = v;
        }
        // stage W chunk: 64 k x 128 cols = 2048 float4
        const float4* wg = (const float4*)W;
        for (int i = tid; i < 2048; i += 256) {
            int r = i >> 5, c4 = i & 31;
            ((float4*)wsh)[i] = wg[(kk + r) * 32 + c4];
        }
        __syncthreads();

#pragma unroll 8
        for (int k = 0; k < 64; k++) {
            float4 wv = ((const float4*)wsh)[k * 32 + tx];
#pragma unroll
            for (int r = 0; r < 8; r++) {
                float xv = xs[(ty * 8 + r) * 64 + k];
                acc[r][0] = fmaf(xv, wv.x, acc[r][0]);
                acc[r][1] = fmaf(xv, wv.y, acc[r][1]);
                acc[r][2] = fmaf(xv, wv.z, acc[r][2]);
                acc[r][3] = fmaf(xv, wv.w, acc[r][3]);
            }
        }
        __syncthreads();
    }

#pragma unroll
    for (int r = 0; r < 8; r++) {
        int row = row0 + ty * 8 + r;
        if (row < N)
            ((float4*)h)[row * 32 + tx] =
                make_float4(acc[r][0], acc[r][1], acc[r][2], acc[r][3]);
    }
}

// ---------------- layer-1 aggregation: agg[d] += h[s] * dinv[s]*dinv[d] ------
// One wave (64 lanes) per edge; lane handles 2 consecutive features (float2).
// Edges e in [0, E) are real edges; e in [E, E+N) are self-loops.
__global__ void agg1_kernel(const int* __restrict__ src, const int* __restrict__ dst,
                            const float* __restrict__ dinv, const float* __restrict__ h,
                            float* __restrict__ agg, int E, int N) {
    long gid = (long)blockIdx.x * blockDim.x + threadIdx.x;
    long total = (long)(E + N) * 64;
    if (gid >= total) return;
    int e = (int)(gid >> 6);
    int l = (int)(gid & 63);
    int s, d;
    float norm;
    if (e < E) {
        s = src[e];
        d = dst[e];
        norm = dinv[s] * dinv[d];
    } else {
        s = d = e - E;
        float dv = dinv[s];
        norm = dv * dv;
    }
    float2 v = ((const float2*)h)[s * 64 + l];
    atomicAdd(&agg[d * 128 + 2 * l],     v.x * norm);
    atomicAdd(&agg[d * 128 + 2 * l + 1], v.y * norm);
}

// ---------------- gemm2: h2[N,16] = relu(agg1 + b1) @ W2[128,16] ----------------
// 16 rows/block, 256 threads (thread = row x col). LDS 16KB.
__global__ __launch_bounds__(256)
void gemm2_kernel(const float* __restrict__ agg1, const float* __restrict__ b1,
                  const float* __restrict__ W2, float* __restrict__ h2, int N) {
    __shared__ float hs[16 * 128];
    __shared__ float w2s[128 * 16];
    const int tid = threadIdx.x;
    const int row0 = blockIdx.x * 16;

    for (int i = tid; i < 512; i += 256)
        ((float4*)w2s)[i] = ((const float4*)W2)[i];

    for (int i = tid; i < 512; i += 256) {
        int r = i >> 5, k4 = i & 31;
        int row = row0 + r;
        float4 v = make_float4(0.f, 0.f, 0.f, 0.f);
        if (row < N) {
            v = ((const float4*)agg1)[row * 32 + k4];
            float4 b = ((const float4*)b1)[k4];
            v.x = fmaxf(v.x + b.x, 0.f);
            v.y = fmaxf(v.y + b.y, 0.f);
            v.z = fmaxf(v.z + b.z, 0.f);
            v.w = fmaxf(v.w + b.w, 0.f);
        }
        ((float4*)hs)[i] = v;
    }
    __syncthreads();

    int r = tid >> 4, c = tid & 15;
    float acc = 0.0f;
#pragma unroll 16
    for (int k = 0; k < 128; k++)
        acc = fmaf(hs[r * 128 + k], w2s[k * 16 + c], acc);

    int row = row0 + r;
    if (row < N) h2[row * 16 + c] = acc;
}

// ---------------- layer-2 aggregation (16 features) ----------------
__global__ void agg2_kernel(const int* __restrict__ src, const int* __restrict__ dst,
                            const float* __restrict__ dinv, const float* __restrict__ h2,
                            float* __restrict__ agg, int E, int N) {
    long gid = (long)blockIdx.x * blockDim.x + threadIdx.x;
    long total = (long)(E + N) * 16;
    if (gid >= total) return;
    int e = (int)(gid >> 4);
    int f = (int)(gid & 15);
    int s, d;
    float norm;
    if (e < E) {
        s = src[e];
        d = dst[e];
        norm = dinv[s] * dinv[d];
    } else {
        s = d = e - E;
        float dv = dinv[s];
        norm = dv * dv;
    }
    atomicAdd(&agg[d * 16 + f], h2[s * 16 + f] * norm);
}

// ---------------- final: out = log_softmax(agg2 + b2, axis=1) ----------------
__global__ void final_kernel(const float* __restrict__ agg2, const float* __restrict__ b2,
                             float* __restrict__ out, int N) {
    int i = blockIdx.x * blockDim.x + threadIdx.x;
    if (i >= N) return;
    float v[16];
    const float4* a4 = (const float4*)agg2 + i * 4;
    const float4* b4 = (const float4*)b2;
#pragma unroll
    for (int j = 0; j < 4; j++) {
        float4 t = a4[j];
        float4 b = b4[j];
        v[4 * j + 0] = t.x + b.x;
        v[4 * j + 1] = t.y + b.y;
        v[4 * j + 2] = t.z + b.z;
        v[4 * j + 3] = t.w + b.w;
    }
    float m = v[0];
#pragma unroll
    for (int j = 1; j < 16; j++) m = fmaxf(m, v[j]);
    float s = 0.0f;
#pragma unroll
    for (int j = 0; j < 16; j++) s += expf(v[j] - m);
    float lse = m + logf(s);
    float4* o4 = (float4*)out + i * 4;
#pragma unroll
    for (int j = 0; j < 4; j++)
        o4[j] = make_float4(v[4 * j + 0] - lse, v[4 * j + 1] - lse,
                            v[4 * j + 2] - lse, v[4 * j + 3] - lse);
}

extern "C" void kernel_launch(void* const* d_in, const int* in_sizes, int n_in,
                              void* d_out, int out_size, void* d_ws, size_t ws_size,
                              hipStream_t stream) {
    const float* x  = (const float*)d_in[0];
    const int*  ei  = (const int*)d_in[1];
    const float* W1 = (const float*)d_in[2];
    const float* b1 = (const float*)d_in[3];
    const float* W2 = (const float*)d_in[4];
    const float* b2 = (const float*)d_in[5];
    float* out = (float*)d_out;

    const int N = in_sizes[0] / 128;   // 50000
    const int E = in_sizes[1] / 2;     // 800000
    const int* src = ei;
    const int* dst = ei + E;

    // Workspace layout (f32):
    //   [0, N)              : deg -> dinv (in place)
    //   h1   = base + N     : N*128   (25.6 MB)
    //   agg1 = h1 + N*128   : N*128   (25.6 MB)
    //   h2   = h1 (reuse; h1 dead after agg1_kernel)  : N*16
    //   agg2 = h1 + N*16 (also inside dead h1 region) : N*16
    float* wsf  = (float*)d_ws;
    float* dinv = wsf;                    // N floats (N*4 = 200000 B, 16B-aligned)
    float* h1   = wsf + N;
    float* agg1 = h1 + (size_t)N * 128;
    float* h2   = h1;
    float* agg2 = h1 + (size_t)N * 16;

    // ---- degree / dinv ----
    hipMemsetAsync(dinv, 0, (size_t)N * sizeof(float), stream);
    deg_kernel<<<(E + 255) / 256, 256, 0, stream>>>(dst, dinv, E);
    dinv_kernel<<<(N + 255) / 256, 256, 0, stream>>>(dinv, N);

    // ---- layer 1 ----
    gemm1_kernel<<<(N + 63) / 64, 256, 0, stream>>>(x, W1, h1, N);
    hipMemsetAsync(agg1, 0, (size_t)N * 128 * sizeof(float), stream);
    {
        long total = (long)(E + N) * 64;
        int blocks = (int)((total + 255) / 256);
        agg1_kernel<<<blocks, 256, 0, stream>>>(src, dst, dinv, h1, agg1, E, N);
    }

    // ---- layer 2 ----
    gemm2_kernel<<<(N + 15) / 16, 256, 0, stream>>>(agg1, b1, W2, h2, N);
    // agg2 region overlaps dead h1 tail; zero it only after agg1_kernel consumed h1
    hipMemsetAsync(agg2, 0, (size_t)N * 16 * sizeof(float), stream);
    {
        long total = (long)(E + N) * 16;
        int blocks = (int)((total + 255) / 256);
        agg2_kernel<<<blocks, 256, 0, stream>>>(src, dst, dinv, h2, agg2, E, N);
    }

    // ---- log_softmax ----
    final_kernel<<<(N + 255) / 256, 256, 0, stream>>>(agg2, b2, out, N);
}

// Round 2
// 352.464 us; speedup vs baseline: 2.6301x; 2.6301x over previous
//
#include <hip/hip_runtime.h>
#include <math.h>

// GCN, N=50000 nodes, E=800000 edges, F_IN=128, H=128, C=16. All f32; edges int32.
//
// Strategy (R2): CSR-by-dst built on device, pull-mode aggregation (no float
// atomics), dinv pre-scaling folded into GEMM epilogues, gemm2 fused into the
// layer-1 pull, log_softmax fused into the layer-2 pull.

// ---------------- histogram of in-degree (real edges) ----------------
__global__ void hist_kernel(const int* __restrict__ dst, int* __restrict__ cnt, int E) {
    int i = blockIdx.x * blockDim.x + threadIdx.x;
    if (i < E) atomicAdd(&cnt[dst[i]], 1);
}

__global__ void dinv_kernel(const int* __restrict__ cnt, float* __restrict__ dinv, int N) {
    int i = blockIdx.x * blockDim.x + threadIdx.x;
    if (i < N) dinv[i] = rsqrtf((float)cnt[i] + 1.0f);  // +1 self-loop; deg >= 1
}

// ---------------- exclusive scan of cnt -> rowptr (single block) ----------------
__global__ __launch_bounds__(1024)
void scan_kernel(const int* __restrict__ cnt, int* __restrict__ rowptr, int N) {
    __shared__ int part[1024];
    int t = threadIdx.x;
    int chunk = (N + 1023) >> 10;
    int beg = t * chunk;
    int end = min(beg + chunk, N);
    int s = 0;
    for (int i = beg; i < end; i++) s += cnt[i];
    part[t] = s;
    __syncthreads();
    for (int off = 1; off < 1024; off <<= 1) {
        int u = (t >= off) ? part[t - off] : 0;
        __syncthreads();
        part[t] += u;
        __syncthreads();
    }
    int run = part[t] - s;  // exclusive prefix for this thread's chunk
    for (int i = beg; i < end; i++) { rowptr[i] = run; run += cnt[i]; }
    if (t == 0) rowptr[N] = part[1023];
}

// ---------------- scatter edges into CSR (int atomics on cursors) ----------------
__global__ void scatter_kernel(const int* __restrict__ src, const int* __restrict__ dst,
                               const int* __restrict__ rowptr, int* __restrict__ cursor,
                               int* __restrict__ colsrc, int E) {
    int e = blockIdx.x * blockDim.x + threadIdx.x;
    if (e >= E) return;
    int d = dst[e];
    int pos = atomicAdd(&cursor[d], 1);
    colsrc[rowptr[d] + pos] = src[e];
}

// ---------------- gemm1: h1s[N,128] = (x @ W1) * dinv[row] ----------------
// 64 rows/block, 256 threads, k in 2 chunks of 64. LDS = 16KB(x) + 32KB(W).
__global__ __launch_bounds__(256)
void gemm1_kernel(const float* __restrict__ x, const float* __restrict__ W,
                  const float* __restrict__ dinv, float* __restrict__ h1s, int N) {
    __shared__ float xs[64 * 64];     // [row][k]
    __shared__ float wsh[64 * 128];   // [k][col]
    const int tid = threadIdx.x;
    const int row0 = blockIdx.x * 64;
    const int ty = tid >> 5;          // 0..7 -> 8 rows each
    const int tx = tid & 31;          // 0..31 -> 4 cols each

    float acc[8][4];
#pragma unroll
    for (int r = 0; r < 8; r++)
#pragma unroll
        for (int c = 0; c < 4; c++) acc[r][c] = 0.0f;

    for (int kk = 0; kk < 128; kk += 64) {
        const float4* xg = (const float4*)x;
        for (int i = tid; i < 1024; i += 256) {
            int r = i >> 4, k4 = i & 15;
            int row = row0 + r;
            float4 v = make_float4(0.f, 0.f, 0.f, 0.f);
            if (row < N) v = xg[row * 32 + (kk >> 2) + k4];
            ((float4*)xs)[i] = v;
        }
        const float4* wg = (const float4*)W;
        for (int i = tid; i < 2048; i += 256) {
            int r = i >> 5, c4 = i & 31;
            ((float4*)wsh)[i] = wg[(kk + r) * 32 + c4];
        }
        __syncthreads();

#pragma unroll 8
        for (int k = 0; k < 64; k++) {
            float4 wv = ((const float4*)wsh)[k * 32 + tx];
#pragma unroll
            for (int r = 0; r < 8; r++) {
                float xv = xs[(ty * 8 + r) * 64 + k];
                acc[r][0] = fmaf(xv, wv.x, acc[r][0]);
                acc[r][1] = fmaf(xv, wv.y, acc[r][1]);
                acc[r][2] = fmaf(xv, wv.z, acc[r][2]);
                acc[r][3] = fmaf(xv, wv.w, acc[r][3]);
            }
        }
        __syncthreads();
    }

#pragma unroll
    for (int r = 0; r < 8; r++) {
        int row = row0 + ty * 8 + r;
        if (row < N) {
            float dv = dinv[row];
            ((float4*)h1s)[row * 32 + tx] =
                make_float4(acc[r][0] * dv, acc[r][1] * dv, acc[r][2] * dv, acc[r][3] * dv);
        }
    }
}

// ---------------- fused layer-1 pull + gemm2 ----------------
// One wave per dst node (4 nodes / 256-thread block). Lane holds 2 features.
// row = relu(dinv[d] * (self + sum_in h1s[src]) + b1); h2s[d] = dinv[d] * (row @ W2).
__global__ __launch_bounds__(256)
void l1_kernel(const int* __restrict__ rowptr, const int* __restrict__ colsrc,
               const float* __restrict__ dinv, const float* __restrict__ h1s,
               const float* __restrict__ b1, const float* __restrict__ W2,
               float* __restrict__ h2s, int N) {
    __shared__ float w2s[128 * 16];   // [k][c], 8 KB
    __shared__ float rows[4][128];    // 2 KB
    const int tid = threadIdx.x;
    for (int i = tid; i < 512; i += 256)
        ((float4*)w2s)[i] = ((const float4*)W2)[i];

    const int wave = tid >> 6, lane = tid & 63;
    const int d = blockIdx.x * 4 + wave;
    const float2* h1f2 = (const float2*)h1s;

    if (d < N) {
        float2 acc = h1f2[d * 64 + lane];  // self-loop term
        int i = rowptr[d], end = rowptr[d + 1];
        for (; i + 4 <= end; i += 4) {
            int s0 = colsrc[i], s1 = colsrc[i + 1], s2 = colsrc[i + 2], s3 = colsrc[i + 3];
            float2 v0 = h1f2[s0 * 64 + lane];
            float2 v1 = h1f2[s1 * 64 + lane];
            float2 v2 = h1f2[s2 * 64 + lane];
            float2 v3 = h1f2[s3 * 64 + lane];
            acc.x += v0.x + v1.x + v2.x + v3.x;
            acc.y += v0.y + v1.y + v2.y + v3.y;
        }
        for (; i < end; i++) {
            float2 v = h1f2[colsrc[i] * 64 + lane];
            acc.x += v.x; acc.y += v.y;
        }
        float dv = dinv[d];
        float2 b = ((const float2*)b1)[lane];
        acc.x = fmaxf(acc.x * dv + b.x, 0.0f);
        acc.y = fmaxf(acc.y * dv + b.y, 0.0f);
        ((float2*)&rows[wave][0])[lane] = acc;
    }
    __syncthreads();
    if (d < N) {
        int c = lane & 15, kg = lane >> 4;  // 4 k-groups of 32
        float p = 0.0f;
#pragma unroll
        for (int k = 0; k < 32; k++) {
            int kk = kg * 32 + k;
            p = fmaf(rows[wave][kk], w2s[kk * 16 + c], p);
        }
        p += __shfl_xor(p, 16, 64);
        p += __shfl_xor(p, 32, 64);
        if (kg == 0) h2s[d * 16 + c] = p * dinv[d];
    }
}

// ---------------- fused layer-2 pull + log_softmax ----------------
// 16 threads per node; lane f handles feature f. Group-of-16 shuffle reductions.
__global__ __launch_bounds__(256)
void l2_kernel(const int* __restrict__ rowptr, const int* __restrict__ colsrc,
               const float* __restrict__ dinv, const float* __restrict__ h2s,
               const float* __restrict__ b2, float* __restrict__ out, int N) {
    int tid = blockIdx.x * blockDim.x + threadIdx.x;
    int d = tid >> 4, f = tid & 15;
    if (d >= N) return;
    float acc = h2s[d * 16 + f];  // self-loop term
    int i = rowptr[d], end = rowptr[d + 1];
    for (; i + 4 <= end; i += 4) {
        int s0 = colsrc[i], s1 = colsrc[i + 1], s2 = colsrc[i + 2], s3 = colsrc[i + 3];
        acc += h2s[s0 * 16 + f] + h2s[s1 * 16 + f] + h2s[s2 * 16 + f] + h2s[s3 * 16 + f];
    }
    for (; i < end; i++) acc += h2s[colsrc[i] * 16 + f];
    float val = acc * dinv[d] + b2[f];

    float m = val;
#pragma unroll
    for (int off = 8; off >= 1; off >>= 1)
        m = fmaxf(m, __shfl_xor(m, off, 16));
    float e = expf(val - m);
#pragma unroll
    for (int off = 8; off >= 1; off >>= 1)
        e += __shfl_xor(e, off, 16);
    out[d * 16 + f] = val - m - logf(e);
}

extern "C" void kernel_launch(void* const* d_in, const int* in_sizes, int n_in,
                              void* d_out, int out_size, void* d_ws, size_t ws_size,
                              hipStream_t stream) {
    const float* x  = (const float*)d_in[0];
    const int*  ei  = (const int*)d_in[1];
    const float* W1 = (const float*)d_in[2];
    const float* b1 = (const float*)d_in[3];
    const float* W2 = (const float*)d_in[4];
    const float* b2 = (const float*)d_in[5];
    float* out = (float*)d_out;

    const int N = in_sizes[0] / 128;   // 50000
    const int E = in_sizes[1] / 2;     // 800000
    const int* src = ei;
    const int* dst = ei + E;

    // Workspace layout (all 16B-aligned: N*4=200000 and E*4=3200000 are /16):
    //   dinv   : N floats
    //   tmp    : N ints   (histogram, then re-zeroed as scatter cursor)
    //   rowptr : N+4 ints
    //   colsrc : E ints
    //   h1s    : N*128 floats (25.6 MB)
    //   h2s    : N*16  floats (3.2 MB)     total ~32.6 MB
    float* wsf    = (float*)d_ws;
    float* dinv   = wsf;
    int*   tmp    = (int*)(wsf + N);
    int*   rowptr = tmp + N;
    int*   colsrc = rowptr + N + 4;
    float* h1s    = (float*)(colsrc + E);
    float* h2s    = h1s + (size_t)N * 128;

    // ---- CSR build + dinv ----
    hipMemsetAsync(tmp, 0, (size_t)N * sizeof(int), stream);
    hist_kernel<<<(E + 255) / 256, 256, 0, stream>>>(dst, tmp, E);
    dinv_kernel<<<(N + 255) / 256, 256, 0, stream>>>(tmp, dinv, N);
    scan_kernel<<<1, 1024, 0, stream>>>(tmp, rowptr, N);
    hipMemsetAsync(tmp, 0, (size_t)N * sizeof(int), stream);
    scatter_kernel<<<(E + 255) / 256, 256, 0, stream>>>(src, dst, rowptr, tmp, colsrc, E);

    // ---- layer 1 feature transform (dinv pre-scaled) ----
    gemm1_kernel<<<(N + 63) / 64, 256, 0, stream>>>(x, W1, dinv, h1s, N);

    // ---- fused pull-aggregation 1 + gemm2 (produces pre-scaled h2s) ----
    l1_kernel<<<(N + 3) / 4, 256, 0, stream>>>(rowptr, colsrc, dinv, h1s, b1, W2, h2s, N);

    // ---- fused pull-aggregation 2 + bias + log_softmax ----
    l2_kernel<<<(N * 16 + 255) / 256, 256, 0, stream>>>(rowptr, colsrc, dinv, h2s, b2, out, N);
}

// Round 3
// 291.324 us; speedup vs baseline: 3.1821x; 1.2099x over previous
//
#include <hip/hip_runtime.h>
#include <math.h>

// GCN, N=50000 nodes, E=800000 edges, F_IN=128, H=128, C=16. All f32; edges int32.
//
// R2: CSR-by-dst pull aggregation (no float atomics), dinv pre-scaling in GEMM
//     epilogues, gemm2 fused into layer-1 pull, log_softmax fused into layer-2.
// R3: single-block scan (76 us, 0.15% occupancy) -> 3-phase multi-block scan.

// ---------------- histogram of in-degree (real edges) ----------------
__global__ void hist_kernel(const int* __restrict__ dst, int* __restrict__ cnt, int E) {
    int i = blockIdx.x * blockDim.x + threadIdx.x;
    if (i < E) atomicAdd(&cnt[dst[i]], 1);
}

__global__ void dinv_kernel(const int* __restrict__ cnt, float* __restrict__ dinv, int N) {
    int i = blockIdx.x * blockDim.x + threadIdx.x;
    if (i < N) dinv[i] = rsqrtf((float)cnt[i] + 1.0f);  // +1 self-loop; deg >= 1
}

// ---------------- 3-phase exclusive scan: cnt[N] -> rowptr[N+1] ----------------
// Phase 1: per-block (256 elems) sums.
__global__ __launch_bounds__(256)
void scan_p1(const int* __restrict__ cnt, int* __restrict__ bsum, int N) {
    __shared__ int sm[256];
    int t = threadIdx.x;
    int i = blockIdx.x * 256 + t;
    sm[t] = (i < N) ? cnt[i] : 0;
    __syncthreads();
#pragma unroll
    for (int off = 128; off >= 1; off >>= 1) {
        if (t < off) sm[t] += sm[t + off];
        __syncthreads();
    }
    if (t == 0) bsum[blockIdx.x] = sm[0];
}

// Phase 2: exclusive scan of block sums (nb <= 256) in place; total -> rowptr[N].
__global__ __launch_bounds__(256)
void scan_p2(int* __restrict__ bsum, int nb, int* __restrict__ rowptrN) {
    __shared__ int sm[256];
    int t = threadIdx.x;
    int v = (t < nb) ? bsum[t] : 0;
    sm[t] = v;
    __syncthreads();
#pragma unroll
    for (int off = 1; off < 256; off <<= 1) {
        int u = (t >= off) ? sm[t - off] : 0;
        __syncthreads();
        sm[t] += u;
        __syncthreads();
    }
    if (t < nb) bsum[t] = sm[t] - v;   // exclusive prefix
    if (t == 255) *rowptrN = sm[255];  // grand total
}

// Phase 3: per-block exclusive scan + block offset -> rowptr[0..N).
__global__ __launch_bounds__(256)
void scan_p3(const int* __restrict__ cnt, const int* __restrict__ bsum,
             int* __restrict__ rowptr, int N) {
    __shared__ int sm[256];
    int t = threadIdx.x;
    int i = blockIdx.x * 256 + t;
    int v = (i < N) ? cnt[i] : 0;
    sm[t] = v;
    __syncthreads();
#pragma unroll
    for (int off = 1; off < 256; off <<= 1) {
        int u = (t >= off) ? sm[t - off] : 0;
        __syncthreads();
        sm[t] += u;
        __syncthreads();
    }
    if (i < N) rowptr[i] = sm[t] - v + bsum[blockIdx.x];
}

// ---------------- scatter edges into CSR (int atomics on cursors) ----------------
__global__ void scatter_kernel(const int* __restrict__ src, const int* __restrict__ dst,
                               const int* __restrict__ rowptr, int* __restrict__ cursor,
                               int* __restrict__ colsrc, int E) {
    int e = blockIdx.x * blockDim.x + threadIdx.x;
    if (e >= E) return;
    int d = dst[e];
    int pos = atomicAdd(&cursor[d], 1);
    colsrc[rowptr[d] + pos] = src[e];
}

// ---------------- gemm1: h1s[N,128] = (x @ W1) * dinv[row] ----------------
// 64 rows/block, 256 threads, k in 2 chunks of 64. LDS = 16KB(x) + 32KB(W).
__global__ __launch_bounds__(256)
void gemm1_kernel(const float* __restrict__ x, const float* __restrict__ W,
                  const float* __restrict__ dinv, float* __restrict__ h1s, int N) {
    __shared__ float xs[64 * 64];     // [row][k]
    __shared__ float wsh[64 * 128];   // [k][col]
    const int tid = threadIdx.x;
    const int row0 = blockIdx.x * 64;
    const int ty = tid >> 5;          // 0..7 -> 8 rows each
    const int tx = tid & 31;          // 0..31 -> 4 cols each

    float acc[8][4];
#pragma unroll
    for (int r = 0; r < 8; r++)
#pragma unroll
        for (int c = 0; c < 4; c++) acc[r][c] = 0.0f;

    for (int kk = 0; kk < 128; kk += 64) {
        const float4* xg = (const float4*)x;
        for (int i = tid; i < 1024; i += 256) {
            int r = i >> 4, k4 = i & 15;
            int row = row0 + r;
            float4 v = make_float4(0.f, 0.f, 0.f, 0.f);
            if (row < N) v = xg[row * 32 + (kk >> 2) + k4];
            ((float4*)xs)[i] = v;
        }
        const float4* wg = (const float4*)W;
        for (int i = tid; i < 2048; i += 256) {
            int r = i >> 5, c4 = i & 31;
            ((float4*)wsh)[i] = wg[(kk + r) * 32 + c4];
        }
        __syncthreads();

#pragma unroll 8
        for (int k = 0; k < 64; k++) {
            float4 wv = ((const float4*)wsh)[k * 32 + tx];
#pragma unroll
            for (int r = 0; r < 8; r++) {
                float xv = xs[(ty * 8 + r) * 64 + k];
                acc[r][0] = fmaf(xv, wv.x, acc[r][0]);
                acc[r][1] = fmaf(xv, wv.y, acc[r][1]);
                acc[r][2] = fmaf(xv, wv.z, acc[r][2]);
                acc[r][3] = fmaf(xv, wv.w, acc[r][3]);
            }
        }
        __syncthreads();
    }

#pragma unroll
    for (int r = 0; r < 8; r++) {
        int row = row0 + ty * 8 + r;
        if (row < N) {
            float dv = dinv[row];
            ((float4*)h1s)[row * 32 + tx] =
                make_float4(acc[r][0] * dv, acc[r][1] * dv, acc[r][2] * dv, acc[r][3] * dv);
        }
    }
}

// ---------------- fused layer-1 pull + gemm2 ----------------
// One wave per dst node (4 nodes / 256-thread block). Lane holds 2 features.
// row = relu(dinv[d] * (self + sum_in h1s[src]) + b1); h2s[d] = dinv[d] * (row @ W2).
__global__ __launch_bounds__(256)
void l1_kernel(const int* __restrict__ rowptr, const int* __restrict__ colsrc,
               const float* __restrict__ dinv, const float* __restrict__ h1s,
               const float* __restrict__ b1, const float* __restrict__ W2,
               float* __restrict__ h2s, int N) {
    __shared__ float w2s[128 * 16];   // [k][c], 8 KB
    __shared__ float rows[4][128];    // 2 KB
    const int tid = threadIdx.x;
    for (int i = tid; i < 512; i += 256)
        ((float4*)w2s)[i] = ((const float4*)W2)[i];

    const int wave = tid >> 6, lane = tid & 63;
    const int d = blockIdx.x * 4 + wave;
    const float2* h1f2 = (const float2*)h1s;

    if (d < N) {
        float2 acc = h1f2[d * 64 + lane];  // self-loop term
        int i = rowptr[d], end = rowptr[d + 1];
        for (; i + 4 <= end; i += 4) {
            int s0 = colsrc[i], s1 = colsrc[i + 1], s2 = colsrc[i + 2], s3 = colsrc[i + 3];
            float2 v0 = h1f2[s0 * 64 + lane];
            float2 v1 = h1f2[s1 * 64 + lane];
            float2 v2 = h1f2[s2 * 64 + lane];
            float2 v3 = h1f2[s3 * 64 + lane];
            acc.x += v0.x + v1.x + v2.x + v3.x;
            acc.y += v0.y + v1.y + v2.y + v3.y;
        }
        for (; i < end; i++) {
            float2 v = h1f2[colsrc[i] * 64 + lane];
            acc.x += v.x; acc.y += v.y;
        }
        float dv = dinv[d];
        float2 b = ((const float2*)b1)[lane];
        acc.x = fmaxf(acc.x * dv + b.x, 0.0f);
        acc.y = fmaxf(acc.y * dv + b.y, 0.0f);
        ((float2*)&rows[wave][0])[lane] = acc;
    }
    __syncthreads();
    if (d < N) {
        int c = lane & 15, kg = lane >> 4;  // 4 k-groups of 32
        float p = 0.0f;
#pragma unroll
        for (int k = 0; k < 32; k++) {
            int kk = kg * 32 + k;
            p = fmaf(rows[wave][kk], w2s[kk * 16 + c], p);
        }
        p += __shfl_xor(p, 16, 64);
        p += __shfl_xor(p, 32, 64);
        if (kg == 0) h2s[d * 16 + c] = p * dinv[d];
    }
}

// ---------------- fused layer-2 pull + log_softmax ----------------
// 16 threads per node; lane f handles feature f. Group-of-16 shuffle reductions.
__global__ __launch_bounds__(256)
void l2_kernel(const int* __restrict__ rowptr, const int* __restrict__ colsrc,
               const float* __restrict__ dinv, const float* __restrict__ h2s,
               const float* __restrict__ b2, float* __restrict__ out, int N) {
    int tid = blockIdx.x * blockDim.x + threadIdx.x;
    int d = tid >> 4, f = tid & 15;
    if (d >= N) return;
    float acc = h2s[d * 16 + f];  // self-loop term
    int i = rowptr[d], end = rowptr[d + 1];
    for (; i + 4 <= end; i += 4) {
        int s0 = colsrc[i], s1 = colsrc[i + 1], s2 = colsrc[i + 2], s3 = colsrc[i + 3];
        acc += h2s[s0 * 16 + f] + h2s[s1 * 16 + f] + h2s[s2 * 16 + f] + h2s[s3 * 16 + f];
    }
    for (; i < end; i++) acc += h2s[colsrc[i] * 16 + f];
    float val = acc * dinv[d] + b2[f];

    float m = val;
#pragma unroll
    for (int off = 8; off >= 1; off >>= 1)
        m = fmaxf(m, __shfl_xor(m, off, 16));
    float e = expf(val - m);
#pragma unroll
    for (int off = 8; off >= 1; off >>= 1)
        e += __shfl_xor(e, off, 16);
    out[d * 16 + f] = val - m - logf(e);
}

extern "C" void kernel_launch(void* const* d_in, const int* in_sizes, int n_in,
                              void* d_out, int out_size, void* d_ws, size_t ws_size,
                              hipStream_t stream) {
    const float* x  = (const float*)d_in[0];
    const int*  ei  = (const int*)d_in[1];
    const float* W1 = (const float*)d_in[2];
    const float* b1 = (const float*)d_in[3];
    const float* W2 = (const float*)d_in[4];
    const float* b2 = (const float*)d_in[5];
    float* out = (float*)d_out;

    const int N = in_sizes[0] / 128;   // 50000
    const int E = in_sizes[1] / 2;     // 800000
    const int* src = ei;
    const int* dst = ei + E;

    // Workspace layout (all 16B-aligned: N*4=200000 and E*4=3200000 are /16):
    //   dinv   : N floats
    //   tmp    : N ints   (histogram, then re-zeroed as scatter cursor)
    //   rowptr : N+4 ints
    //   bsum   : 256 ints (block sums for the scan)
    //   colsrc : E ints
    //   h1s    : N*128 floats (25.6 MB)
    //   h2s    : N*16  floats (3.2 MB)     total ~32.6 MB
    float* wsf    = (float*)d_ws;
    float* dinv   = wsf;
    int*   tmp    = (int*)(wsf + N);
    int*   rowptr = tmp + N;
    int*   bsum   = rowptr + N + 4;
    int*   colsrc = bsum + 256;
    float* h1s    = (float*)(colsrc + E);
    float* h2s    = h1s + (size_t)N * 128;

    const int nb = (N + 255) / 256;    // 196 scan blocks (<= 256 required)

    // ---- CSR build + dinv ----
    hipMemsetAsync(tmp, 0, (size_t)N * sizeof(int), stream);
    hist_kernel<<<(E + 255) / 256, 256, 0, stream>>>(dst, tmp, E);
    dinv_kernel<<<(N + 255) / 256, 256, 0, stream>>>(tmp, dinv, N);
    scan_p1<<<nb, 256, 0, stream>>>(tmp, bsum, N);
    scan_p2<<<1, 256, 0, stream>>>(bsum, nb, rowptr + N);
    scan_p3<<<nb, 256, 0, stream>>>(tmp, bsum, rowptr, N);
    hipMemsetAsync(tmp, 0, (size_t)N * sizeof(int), stream);
    scatter_kernel<<<(E + 255) / 256, 256, 0, stream>>>(src, dst, rowptr, tmp, colsrc, E);

    // ---- layer 1 feature transform (dinv pre-scaled) ----
    gemm1_kernel<<<(N + 63) / 64, 256, 0, stream>>>(x, W1, dinv, h1s, N);

    // ---- fused pull-aggregation 1 + gemm2 (produces pre-scaled h2s) ----
    l1_kernel<<<(N + 3) / 4, 256, 0, stream>>>(rowptr, colsrc, dinv, h1s, b1, W2, h2s, N);

    // ---- fused pull-aggregation 2 + bias + log_softmax ----
    l2_kernel<<<(N * 16 + 255) / 256, 256, 0, stream>>>(rowptr, colsrc, dinv, h2s, b2, out, N);
}

// Round 4
// 272.708 us; speedup vs baseline: 3.3993x; 1.0683x over previous
//
#include <hip/hip_runtime.h>
#include <math.h>

// GCN, N=50000 nodes, E=800000 edges, F_IN=128, H=128, C=16. f32 in/out; edges int32.
//
// R2: CSR-by-dst pull aggregation (no float atomics), dinv pre-scaling in GEMM
//     epilogues, gemm2 fused into layer-1 pull, log_softmax fused into layer-2.
// R3: 3-phase multi-block scan (single-block scan was 76 us at 0.15% occupancy).
// R4: h1 staged as packed bf16 (halves 435 MB gather volume; fp32 accumulate);
//     w2s k-loop interleaved kk=4k+kg to kill 4-way LDS bank conflict.

__device__ __forceinline__ unsigned pack_bf16x2(float a, float b) {
    unsigned ua = __float_as_uint(a), ub = __float_as_uint(b);
    ua = (ua + 0x7fffu + ((ua >> 16) & 1u)) >> 16;   // RNE
    ub = (ub + 0x7fffu + ((ub >> 16) & 1u)) >> 16;
    return (ub << 16) | ua;
}

__device__ __forceinline__ float2 unpack_bf16x2(unsigned u) {
    return make_float2(__uint_as_float(u << 16), __uint_as_float(u & 0xffff0000u));
}

// ---------------- histogram of in-degree (real edges) ----------------
__global__ void hist_kernel(const int* __restrict__ dst, int* __restrict__ cnt, int E) {
    int i = blockIdx.x * blockDim.x + threadIdx.x;
    if (i < E) atomicAdd(&cnt[dst[i]], 1);
}

__global__ void dinv_kernel(const int* __restrict__ cnt, float* __restrict__ dinv, int N) {
    int i = blockIdx.x * blockDim.x + threadIdx.x;
    if (i < N) dinv[i] = rsqrtf((float)cnt[i] + 1.0f);  // +1 self-loop; deg >= 1
}

// ---------------- 3-phase exclusive scan: cnt[N] -> rowptr[N+1] ----------------
__global__ __launch_bounds__(256)
void scan_p1(const int* __restrict__ cnt, int* __restrict__ bsum, int N) {
    __shared__ int sm[256];
    int t = threadIdx.x;
    int i = blockIdx.x * 256 + t;
    sm[t] = (i < N) ? cnt[i] : 0;
    __syncthreads();
#pragma unroll
    for (int off = 128; off >= 1; off >>= 1) {
        if (t < off) sm[t] += sm[t + off];
        __syncthreads();
    }
    if (t == 0) bsum[blockIdx.x] = sm[0];
}

__global__ __launch_bounds__(256)
void scan_p2(int* __restrict__ bsum, int nb, int* __restrict__ rowptrN) {
    __shared__ int sm[256];
    int t = threadIdx.x;
    int v = (t < nb) ? bsum[t] : 0;
    sm[t] = v;
    __syncthreads();
#pragma unroll
    for (int off = 1; off < 256; off <<= 1) {
        int u = (t >= off) ? sm[t - off] : 0;
        __syncthreads();
        sm[t] += u;
        __syncthreads();
    }
    if (t < nb) bsum[t] = sm[t] - v;   // exclusive prefix
    if (t == 255) *rowptrN = sm[255];  // grand total
}

__global__ __launch_bounds__(256)
void scan_p3(const int* __restrict__ cnt, const int* __restrict__ bsum,
             int* __restrict__ rowptr, int N) {
    __shared__ int sm[256];
    int t = threadIdx.x;
    int i = blockIdx.x * 256 + t;
    int v = (i < N) ? cnt[i] : 0;
    sm[t] = v;
    __syncthreads();
#pragma unroll
    for (int off = 1; off < 256; off <<= 1) {
        int u = (t >= off) ? sm[t - off] : 0;
        __syncthreads();
        sm[t] += u;
        __syncthreads();
    }
    if (i < N) rowptr[i] = sm[t] - v + bsum[blockIdx.x];
}

// ---------------- scatter edges into CSR (int atomics on cursors) ----------------
__global__ void scatter_kernel(const int* __restrict__ src, const int* __restrict__ dst,
                               const int* __restrict__ rowptr, int* __restrict__ cursor,
                               int* __restrict__ colsrc, int E) {
    int e = blockIdx.x * blockDim.x + threadIdx.x;
    if (e >= E) return;
    int d = dst[e];
    int pos = atomicAdd(&cursor[d], 1);
    colsrc[rowptr[d] + pos] = src[e];
}

// ---------------- gemm1: h1b[N,128 bf16] = pack((x @ W1) * dinv[row]) ----------------
// 64 rows/block, 256 threads, k in 2 chunks of 64. LDS = 16KB(x) + 32KB(W).
__global__ __launch_bounds__(256)
void gemm1_kernel(const float* __restrict__ x, const float* __restrict__ W,
                  const float* __restrict__ dinv, unsigned* __restrict__ h1b, int N) {
    __shared__ float xs[64 * 64];     // [row][k]
    __shared__ float wsh[64 * 128];   // [k][col]
    const int tid = threadIdx.x;
    const int row0 = blockIdx.x * 64;
    const int ty = tid >> 5;          // 0..7 -> 8 rows each
    const int tx = tid & 31;          // 0..31 -> 4 cols each

    float acc[8][4];
#pragma unroll
    for (int r = 0; r < 8; r++)
#pragma unroll
        for (int c = 0; c < 4; c++) acc[r][c] = 0.0f;

    for (int kk = 0; kk < 128; kk += 64) {
        const float4* xg = (const float4*)x;
        for (int i = tid; i < 1024; i += 256) {
            int r = i >> 4, k4 = i & 15;
            int row = row0 + r;
            float4 v = make_float4(0.f, 0.f, 0.f, 0.f);
            if (row < N) v = xg[row * 32 + (kk >> 2) + k4];
            ((float4*)xs)[i] = v;
        }
        const float4* wg = (const float4*)W;
        for (int i = tid; i < 2048; i += 256) {
            int r = i >> 5, c4 = i & 31;
            ((float4*)wsh)[i] = wg[(kk + r) * 32 + c4];
        }
        __syncthreads();

#pragma unroll 8
        for (int k = 0; k < 64; k++) {
            float4 wv = ((const float4*)wsh)[k * 32 + tx];
#pragma unroll
            for (int r = 0; r < 8; r++) {
                float xv = xs[(ty * 8 + r) * 64 + k];
                acc[r][0] = fmaf(xv, wv.x, acc[r][0]);
                acc[r][1] = fmaf(xv, wv.y, acc[r][1]);
                acc[r][2] = fmaf(xv, wv.z, acc[r][2]);
                acc[r][3] = fmaf(xv, wv.w, acc[r][3]);
            }
        }
        __syncthreads();
    }

#pragma unroll
    for (int r = 0; r < 8; r++) {
        int row = row0 + ty * 8 + r;
        if (row < N) {
            float dv = dinv[row];
            uint2 p;
            p.x = pack_bf16x2(acc[r][0] * dv, acc[r][1] * dv);
            p.y = pack_bf16x2(acc[r][2] * dv, acc[r][3] * dv);
            ((uint2*)h1b)[row * 32 + tx] = p;
        }
    }
}

// ---------------- fused layer-1 pull + gemm2 ----------------
// One wave per dst node (4 nodes / 256-thread block). Lane holds 2 features (bf16x2).
// row = relu(dinv[d] * (self + sum_in h1b[src]) + b1); h2s[d] = dinv[d] * (row @ W2).
__global__ __launch_bounds__(256)
void l1_kernel(const int* __restrict__ rowptr, const int* __restrict__ colsrc,
               const float* __restrict__ dinv, const unsigned* __restrict__ h1b,
               const float* __restrict__ b1, const float* __restrict__ W2,
               float* __restrict__ h2s, int N) {
    __shared__ float w2s[128 * 16];   // [k][c], 8 KB
    __shared__ float rows[4][128];    // 2 KB
    const int tid = threadIdx.x;
    for (int i = tid; i < 512; i += 256)
        ((float4*)w2s)[i] = ((const float4*)W2)[i];

    const int wave = tid >> 6, lane = tid & 63;
    const int d = blockIdx.x * 4 + wave;

    if (d < N) {
        float2 acc = unpack_bf16x2(h1b[(size_t)d * 64 + lane]);  // self-loop term
        int i = rowptr[d], end = rowptr[d + 1];
        for (; i + 4 <= end; i += 4) {
            int s0 = colsrc[i], s1 = colsrc[i + 1], s2 = colsrc[i + 2], s3 = colsrc[i + 3];
            float2 v0 = unpack_bf16x2(h1b[(size_t)s0 * 64 + lane]);
            float2 v1 = unpack_bf16x2(h1b[(size_t)s1 * 64 + lane]);
            float2 v2 = unpack_bf16x2(h1b[(size_t)s2 * 64 + lane]);
            float2 v3 = unpack_bf16x2(h1b[(size_t)s3 * 64 + lane]);
            acc.x += v0.x + v1.x + v2.x + v3.x;
            acc.y += v0.y + v1.y + v2.y + v3.y;
        }
        for (; i < end; i++) {
            float2 v = unpack_bf16x2(h1b[(size_t)colsrc[i] * 64 + lane]);
            acc.x += v.x; acc.y += v.y;
        }
        float dv = dinv[d];
        float2 b = ((const float2*)b1)[lane];
        acc.x = fmaxf(acc.x * dv + b.x, 0.0f);
        acc.y = fmaxf(acc.y * dv + b.y, 0.0f);
        ((float2*)&rows[wave][0])[lane] = acc;
    }
    __syncthreads();
    if (d < N) {
        int c = lane & 15, kg = lane >> 4;
        float p = 0.0f;
        // kk = 4k+kg interleave: the 4 k-groups read banks {c, c+16} -> 2-way
        // aliasing only (free); straight kk=kg*32+k was a 4-way conflict.
#pragma unroll
        for (int k = 0; k < 32; k++) {
            int kk = 4 * k + kg;
            p = fmaf(rows[wave][kk], w2s[kk * 16 + c], p);
        }
        p += __shfl_xor(p, 16, 64);
        p += __shfl_xor(p, 32, 64);
        if (kg == 0) h2s[d * 16 + c] = p * dinv[d];
    }
}

// ---------------- fused layer-2 pull + log_softmax ----------------
// 16 threads per node; lane f handles feature f. Group-of-16 shuffle reductions.
__global__ __launch_bounds__(256)
void l2_kernel(const int* __restrict__ rowptr, const int* __restrict__ colsrc,
               const float* __restrict__ dinv, const float* __restrict__ h2s,
               const float* __restrict__ b2, float* __restrict__ out, int N) {
    int tid = blockIdx.x * blockDim.x + threadIdx.x;
    int d = tid >> 4, f = tid & 15;
    if (d >= N) return;
    float acc = h2s[d * 16 + f];  // self-loop term
    int i = rowptr[d], end = rowptr[d + 1];
    for (; i + 4 <= end; i += 4) {
        int s0 = colsrc[i], s1 = colsrc[i + 1], s2 = colsrc[i + 2], s3 = colsrc[i + 3];
        acc += h2s[s0 * 16 + f] + h2s[s1 * 16 + f] + h2s[s2 * 16 + f] + h2s[s3 * 16 + f];
    }
    for (; i < end; i++) acc += h2s[colsrc[i] * 16 + f];
    float val = acc * dinv[d] + b2[f];

    float m = val;
#pragma unroll
    for (int off = 8; off >= 1; off >>= 1)
        m = fmaxf(m, __shfl_xor(m, off, 16));
    float e = expf(val - m);
#pragma unroll
    for (int off = 8; off >= 1; off >>= 1)
        e += __shfl_xor(e, off, 16);
    out[d * 16 + f] = val - m - logf(e);
}

extern "C" void kernel_launch(void* const* d_in, const int* in_sizes, int n_in,
                              void* d_out, int out_size, void* d_ws, size_t ws_size,
                              hipStream_t stream) {
    const float* x  = (const float*)d_in[0];
    const int*  ei  = (const int*)d_in[1];
    const float* W1 = (const float*)d_in[2];
    const float* b1 = (const float*)d_in[3];
    const float* W2 = (const float*)d_in[4];
    const float* b2 = (const float*)d_in[5];
    float* out = (float*)d_out;

    const int N = in_sizes[0] / 128;   // 50000
    const int E = in_sizes[1] / 2;     // 800000
    const int* src = ei;
    const int* dst = ei + E;

    // Workspace layout (all 16B-aligned):
    //   dinv   : N floats
    //   tmp    : N ints   (histogram, then re-zeroed as scatter cursor)
    //   rowptr : N+4 ints
    //   bsum   : 256 ints
    //   colsrc : E ints
    //   h1b    : N*64 uints (12.8 MB, packed bf16x2)
    //   h2s    : N*16 floats (3.2 MB)       total ~19.8 MB
    float*    wsf    = (float*)d_ws;
    float*    dinv   = wsf;
    int*      tmp    = (int*)(wsf + N);
    int*      rowptr = tmp + N;
    int*      bsum   = rowptr + N + 4;
    int*      colsrc = bsum + 256;
    unsigned* h1b    = (unsigned*)(colsrc + E);
    float*    h2s    = (float*)(h1b + (size_t)N * 64);

    const int nb = (N + 255) / 256;    // 196 scan blocks (<= 256 required)

    // ---- CSR build + dinv ----
    hipMemsetAsync(tmp, 0, (size_t)N * sizeof(int), stream);
    hist_kernel<<<(E + 255) / 256, 256, 0, stream>>>(dst, tmp, E);
    dinv_kernel<<<(N + 255) / 256, 256, 0, stream>>>(tmp, dinv, N);
    scan_p1<<<nb, 256, 0, stream>>>(tmp, bsum, N);
    scan_p2<<<1, 256, 0, stream>>>(bsum, nb, rowptr + N);
    scan_p3<<<nb, 256, 0, stream>>>(tmp, bsum, rowptr, N);
    hipMemsetAsync(tmp, 0, (size_t)N * sizeof(int), stream);
    scatter_kernel<<<(E + 255) / 256, 256, 0, stream>>>(src, dst, rowptr, tmp, colsrc, E);

    // ---- layer 1 feature transform (dinv pre-scaled, bf16-packed) ----
    gemm1_kernel<<<(N + 63) / 64, 256, 0, stream>>>(x, W1, dinv, h1b, N);

    // ---- fused pull-aggregation 1 + gemm2 (produces pre-scaled h2s) ----
    l1_kernel<<<(N + 3) / 4, 256, 0, stream>>>(rowptr, colsrc, dinv, h1b, b1, W2, h2s, N);

    // ---- fused pull-aggregation 2 + bias + log_softmax ----
    l2_kernel<<<(N * 16 + 255) / 256, 256, 0, stream>>>(rowptr, colsrc, dinv, h2s, b2, out, N);
}

// Round 5
// 250.770 us; speedup vs baseline: 3.6967x; 1.0875x over previous
//
#include <hip/hip_runtime.h>
#include <math.h>

// GCN, N=50000 nodes, E=800000 edges, F_IN=128, H=128, C=16. f32 in/out; edges int32.
//
// R2: CSR-by-dst pull aggregation (no float atomics), dinv pre-scaling in GEMM
//     epilogues, gemm2 fused into layer-1 pull, log_softmax fused into layer-2.
// R3: 3-phase multi-block scan.
// R4: h1 staged as packed bf16; w2s k-interleave kills 4-way LDS conflict.
// R5: CSR scatter rewritten as 2-level counting sort (LDS-staged binning +
//     per-bucket LDS-cursor scatter) to kill 17x cross-XCD write amplification
//     (WRITE_SIZE was 55.5 MB for a 3.2 MB output); l1 gather loop unroll 8.

#define NBUCKET_SHIFT 8                   // bucket = dst >> 8 (256 nodes/bucket)
#define BIN_CHUNK 4096                    // edges staged per bin block

__device__ __forceinline__ unsigned pack_bf16x2(float a, float b) {
    unsigned ua = __float_as_uint(a), ub = __float_as_uint(b);
    ua = (ua + 0x7fffu + ((ua >> 16) & 1u)) >> 16;   // RNE
    ub = (ub + 0x7fffu + ((ub >> 16) & 1u)) >> 16;
    return (ub << 16) | ua;
}

__device__ __forceinline__ float2 unpack_bf16x2(unsigned u) {
    return make_float2(__uint_as_float(u << 16), __uint_as_float(u & 0xffff0000u));
}

// ---------------- histogram of in-degree (real edges) ----------------
__global__ void hist_kernel(const int* __restrict__ dst, int* __restrict__ cnt, int E) {
    int i = blockIdx.x * blockDim.x + threadIdx.x;
    if (i < E) atomicAdd(&cnt[dst[i]], 1);
}

__global__ void dinv_kernel(const int* __restrict__ cnt, float* __restrict__ dinv, int N) {
    int i = blockIdx.x * blockDim.x + threadIdx.x;
    if (i < N) dinv[i] = rsqrtf((float)cnt[i] + 1.0f);  // +1 self-loop; deg >= 1
}

// ---------------- 3-phase exclusive scan: cnt[N] -> rowptr[N+1] ----------------
__global__ __launch_bounds__(256)
void scan_p1(const int* __restrict__ cnt, int* __restrict__ bsum, int N) {
    __shared__ int sm[256];
    int t = threadIdx.x;
    int i = blockIdx.x * 256 + t;
    sm[t] = (i < N) ? cnt[i] : 0;
    __syncthreads();
#pragma unroll
    for (int off = 128; off >= 1; off >>= 1) {
        if (t < off) sm[t] += sm[t + off];
        __syncthreads();
    }
    if (t == 0) bsum[blockIdx.x] = sm[0];
}

__global__ __launch_bounds__(256)
void scan_p2(int* __restrict__ bsum, int nb, int* __restrict__ rowptrN) {
    __shared__ int sm[256];
    int t = threadIdx.x;
    int v = (t < nb) ? bsum[t] : 0;
    sm[t] = v;
    __syncthreads();
#pragma unroll
    for (int off = 1; off < 256; off <<= 1) {
        int u = (t >= off) ? sm[t - off] : 0;
        __syncthreads();
        sm[t] += u;
        __syncthreads();
    }
    if (t < nb) bsum[t] = sm[t] - v;   // exclusive prefix
    if (t == 255) *rowptrN = sm[255];  // grand total
}

__global__ __launch_bounds__(256)
void scan_p3(const int* __restrict__ cnt, const int* __restrict__ bsum,
             int* __restrict__ rowptr, int N) {
    __shared__ int sm[256];
    int t = threadIdx.x;
    int i = blockIdx.x * 256 + t;
    int v = (i < N) ? cnt[i] : 0;
    sm[t] = v;
    __syncthreads();
#pragma unroll
    for (int off = 1; off < 256; off <<= 1) {
        int u = (t >= off) ? sm[t - off] : 0;
        __syncthreads();
        sm[t] += u;
        __syncthreads();
    }
    if (i < N) rowptr[i] = sm[t] - v + bsum[blockIdx.x];
}

// ---------------- bucket cursor init: bcur[b] = rowptr[b<<8] ----------------
__global__ void bcur_init_kernel(const int* __restrict__ rowptr, int* __restrict__ bcur,
                                 int nbuckets, int N) {
    int b = blockIdx.x * blockDim.x + threadIdx.x;
    if (b < nbuckets) {
        int node = b << NBUCKET_SHIFT;
        bcur[b] = rowptr[node < N ? node : N];
    }
}

// ---------------- phase 1: bin edges into coarse buckets (LDS-staged) ----------
// Each block stages BIN_CHUNK edges in LDS, counts per bucket, reserves a
// contiguous range per bucket via ONE atomicAdd each, then writes (src,dst)
// pairs bucket-contiguously. Runs are written by a single CU -> no line bounce.
__global__ __launch_bounds__(256)
void bin_kernel(const int* __restrict__ src, const int* __restrict__ dst,
                int* __restrict__ bcur, uint2* __restrict__ pairs, int E, int nbuckets) {
    __shared__ uint2 spair[BIN_CHUNK];   // 32 KB
    __shared__ int bcnt[256];
    __shared__ int bbase[256];
    const int tid = threadIdx.x;
    const int e0 = blockIdx.x * BIN_CHUNK;
    const int cnt = min(BIN_CHUNK, E - e0);

    if (tid < nbuckets) bcnt[tid] = 0;
    __syncthreads();

    for (int i = tid; i < cnt; i += 256) {
        int s = src[e0 + i], d = dst[e0 + i];
        spair[i] = make_uint2((unsigned)s, (unsigned)d);
        atomicAdd(&bcnt[d >> NBUCKET_SHIFT], 1);
    }
    __syncthreads();

    if (tid < nbuckets) {
        int c = bcnt[tid];
        bbase[tid] = (c > 0) ? atomicAdd(&bcur[tid], c) : 0;
        bcnt[tid] = 0;   // reuse as local cursor
    }
    __syncthreads();

    for (int i = tid; i < cnt; i += 256) {
        uint2 p = spair[i];
        int b = (int)(p.y >> NBUCKET_SHIFT);
        int off = atomicAdd(&bcnt[b], 1);
        pairs[bbase[b] + off] = p;
    }
}

// ---------------- phase 2: per-bucket scatter with LDS per-dst cursors --------
// One block per bucket. Bucket b owns dst nodes [b<<8, b<<8+256) and the pair
// range [rowptr[b<<8], rowptr[next]) (bucket ranges partition CSR space).
// Random 4B colsrc writes stay within the bucket's ~17 KB span, one CU only.
__global__ __launch_bounds__(256)
void bucket_scatter_kernel(const int* __restrict__ rowptr, const uint2* __restrict__ pairs,
                           int* __restrict__ colsrc, int N) {
    __shared__ int cur[256];
    const int tid = threadIdx.x;
    const int nb0 = blockIdx.x << NBUCKET_SHIFT;
    const int nodes = min(256, N - nb0);
    if (tid < nodes) cur[tid] = rowptr[nb0 + tid];
    __syncthreads();

    const int lo = rowptr[nb0];
    const int hi = rowptr[(nb0 + 256 < N) ? nb0 + 256 : N];
    for (int i = lo + tid; i < hi; i += 256) {
        uint2 p = pairs[i];
        int pos = atomicAdd(&cur[(int)p.y - nb0], 1);
        colsrc[pos] = (int)p.x;
    }
}

// ---------------- gemm1: h1b[N,128 bf16] = pack((x @ W1) * dinv[row]) ----------------
__global__ __launch_bounds__(256)
void gemm1_kernel(const float* __restrict__ x, const float* __restrict__ W,
                  const float* __restrict__ dinv, unsigned* __restrict__ h1b, int N) {
    __shared__ float xs[64 * 64];     // [row][k]
    __shared__ float wsh[64 * 128];   // [k][col]
    const int tid = threadIdx.x;
    const int row0 = blockIdx.x * 64;
    const int ty = tid >> 5;          // 0..7 -> 8 rows each
    const int tx = tid & 31;          // 0..31 -> 4 cols each

    float acc[8][4];
#pragma unroll
    for (int r = 0; r < 8; r++)
#pragma unroll
        for (int c = 0; c < 4; c++) acc[r][c] = 0.0f;

    for (int kk = 0; kk < 128; kk += 64) {
        const float4* xg = (const float4*)x;
        for (int i = tid; i < 1024; i += 256) {
            int r = i >> 4, k4 = i & 15;
            int row = row0 + r;
            float4 v = make_float4(0.f, 0.f, 0.f, 0.f);
            if (row < N) v = xg[row * 32 + (kk >> 2) + k4];
            ((float4*)xs)[i] = v;
        }
        const float4* wg = (const float4*)W;
        for (int i = tid; i < 2048; i += 256) {
            int r = i >> 5, c4 = i & 31;
            ((float4*)wsh)[i] = wg[(kk + r) * 32 + c4];
        }
        __syncthreads();

#pragma unroll 8
        for (int k = 0; k < 64; k++) {
            float4 wv = ((const float4*)wsh)[k * 32 + tx];
#pragma unroll
            for (int r = 0; r < 8; r++) {
                float xv = xs[(ty * 8 + r) * 64 + k];
                acc[r][0] = fmaf(xv, wv.x, acc[r][0]);
                acc[r][1] = fmaf(xv, wv.y, acc[r][1]);
                acc[r][2] = fmaf(xv, wv.z, acc[r][2]);
                acc[r][3] = fmaf(xv, wv.w, acc[r][3]);
            }
        }
        __syncthreads();
    }

#pragma unroll
    for (int r = 0; r < 8; r++) {
        int row = row0 + ty * 8 + r;
        if (row < N) {
            float dv = dinv[row];
            uint2 p;
            p.x = pack_bf16x2(acc[r][0] * dv, acc[r][1] * dv);
            p.y = pack_bf16x2(acc[r][2] * dv, acc[r][3] * dv);
            ((uint2*)h1b)[row * 32 + tx] = p;
        }
    }
}

// ---------------- fused layer-1 pull + gemm2 ----------------
// One wave per dst node (4 nodes / 256-thread block). Lane holds 2 features (bf16x2).
__global__ __launch_bounds__(256)
void l1_kernel(const int* __restrict__ rowptr, const int* __restrict__ colsrc,
               const float* __restrict__ dinv, const unsigned* __restrict__ h1b,
               const float* __restrict__ b1, const float* __restrict__ W2,
               float* __restrict__ h2s, int N) {
    __shared__ float w2s[128 * 16];   // [k][c], 8 KB
    __shared__ float rows[4][128];    // 2 KB
    const int tid = threadIdx.x;
    for (int i = tid; i < 512; i += 256)
        ((float4*)w2s)[i] = ((const float4*)W2)[i];

    const int wave = tid >> 6, lane = tid & 63;
    const int d = blockIdx.x * 4 + wave;

    if (d < N) {
        float2 a0 = unpack_bf16x2(h1b[(size_t)d * 64 + lane]);  // self-loop term
        float2 a1 = make_float2(0.f, 0.f);
        int i = rowptr[d], end = rowptr[d + 1];
        for (; i + 8 <= end; i += 8) {
            int s0 = colsrc[i],     s1 = colsrc[i + 1], s2 = colsrc[i + 2], s3 = colsrc[i + 3];
            int s4 = colsrc[i + 4], s5 = colsrc[i + 5], s6 = colsrc[i + 6], s7 = colsrc[i + 7];
            float2 v0 = unpack_bf16x2(h1b[(size_t)s0 * 64 + lane]);
            float2 v1 = unpack_bf16x2(h1b[(size_t)s1 * 64 + lane]);
            float2 v2 = unpack_bf16x2(h1b[(size_t)s2 * 64 + lane]);
            float2 v3 = unpack_bf16x2(h1b[(size_t)s3 * 64 + lane]);
            float2 v4 = unpack_bf16x2(h1b[(size_t)s4 * 64 + lane]);
            float2 v5 = unpack_bf16x2(h1b[(size_t)s5 * 64 + lane]);
            float2 v6 = unpack_bf16x2(h1b[(size_t)s6 * 64 + lane]);
            float2 v7 = unpack_bf16x2(h1b[(size_t)s7 * 64 + lane]);
            a0.x += (v0.x + v2.x) + (v4.x + v6.x);
            a0.y += (v0.y + v2.y) + (v4.y + v6.y);
            a1.x += (v1.x + v3.x) + (v5.x + v7.x);
            a1.y += (v1.y + v3.y) + (v5.y + v7.y);
        }
        for (; i < end; i++) {
            float2 v = unpack_bf16x2(h1b[(size_t)colsrc[i] * 64 + lane]);
            a0.x += v.x; a0.y += v.y;
        }
        float2 acc = make_float2(a0.x + a1.x, a0.y + a1.y);
        float dv = dinv[d];
        float2 b = ((const float2*)b1)[lane];
        acc.x = fmaxf(acc.x * dv + b.x, 0.0f);
        acc.y = fmaxf(acc.y * dv + b.y, 0.0f);
        ((float2*)&rows[wave][0])[lane] = acc;
    }
    __syncthreads();
    if (d < N) {
        int c = lane & 15, kg = lane >> 4;
        float p = 0.0f;
        // kk = 4k+kg interleave: 2-way LDS aliasing only (free per m136).
#pragma unroll
        for (int k = 0; k < 32; k++) {
            int kk = 4 * k + kg;
            p = fmaf(rows[wave][kk], w2s[kk * 16 + c], p);
        }
        p += __shfl_xor(p, 16, 64);
        p += __shfl_xor(p, 32, 64);
        if (kg == 0) h2s[d * 16 + c] = p * dinv[d];
    }
}

// ---------------- fused layer-2 pull + log_softmax ----------------
__global__ __launch_bounds__(256)
void l2_kernel(const int* __restrict__ rowptr, const int* __restrict__ colsrc,
               const float* __restrict__ dinv, const float* __restrict__ h2s,
               const float* __restrict__ b2, float* __restrict__ out, int N) {
    int tid = blockIdx.x * blockDim.x + threadIdx.x;
    int d = tid >> 4, f = tid & 15;
    if (d >= N) return;
    float acc = h2s[d * 16 + f];  // self-loop term
    int i = rowptr[d], end = rowptr[d + 1];
    for (; i + 4 <= end; i += 4) {
        int s0 = colsrc[i], s1 = colsrc[i + 1], s2 = colsrc[i + 2], s3 = colsrc[i + 3];
        acc += h2s[s0 * 16 + f] + h2s[s1 * 16 + f] + h2s[s2 * 16 + f] + h2s[s3 * 16 + f];
    }
    for (; i < end; i++) acc += h2s[colsrc[i] * 16 + f];
    float val = acc * dinv[d] + b2[f];

    float m = val;
#pragma unroll
    for (int off = 8; off >= 1; off >>= 1)
        m = fmaxf(m, __shfl_xor(m, off, 16));
    float e = expf(val - m);
#pragma unroll
    for (int off = 8; off >= 1; off >>= 1)
        e += __shfl_xor(e, off, 16);
    out[d * 16 + f] = val - m - logf(e);
}

extern "C" void kernel_launch(void* const* d_in, const int* in_sizes, int n_in,
                              void* d_out, int out_size, void* d_ws, size_t ws_size,
                              hipStream_t stream) {
    const float* x  = (const float*)d_in[0];
    const int*  ei  = (const int*)d_in[1];
    const float* W1 = (const float*)d_in[2];
    const float* b1 = (const float*)d_in[3];
    const float* W2 = (const float*)d_in[4];
    const float* b2 = (const float*)d_in[5];
    float* out = (float*)d_out;

    const int N = in_sizes[0] / 128;   // 50000
    const int E = in_sizes[1] / 2;     // 800000
    const int* src = ei;
    const int* dst = ei + E;
    const int nbuckets = (N + 255) >> NBUCKET_SHIFT;   // 196 (<= 256 required)

    // Workspace layout:
    //   dinv   : N floats
    //   tmp    : N ints (histogram)
    //   rowptr : N+4 ints
    //   bsum   : 256 ints
    //   bcur   : 256 ints (bucket cursors)
    //   colsrc : E ints
    //   pairs  : E uint2 (6.4 MB; offset is 8B-aligned by construction)
    //   h1b    : N*64 uints (12.8 MB, packed bf16x2)
    //   h2s    : N*16 floats (3.2 MB)      total ~26 MB
    float*    wsf    = (float*)d_ws;
    float*    dinv   = wsf;
    int*      tmp    = (int*)(wsf + N);
    int*      rowptr = tmp + N;
    int*      bsum   = rowptr + N + 4;
    int*      bcur   = bsum + 256;
    int*      colsrc = bcur + 256;
    uint2*    pairs  = (uint2*)(colsrc + E);
    unsigned* h1b    = (unsigned*)(pairs + E);
    float*    h2s    = (float*)(h1b + (size_t)N * 64);

    const int nb = (N + 255) / 256;    // 196 scan blocks

    // ---- degree + rowptr ----
    hipMemsetAsync(tmp, 0, (size_t)N * sizeof(int), stream);
    hist_kernel<<<(E + 255) / 256, 256, 0, stream>>>(dst, tmp, E);
    dinv_kernel<<<(N + 255) / 256, 256, 0, stream>>>(tmp, dinv, N);
    scan_p1<<<nb, 256, 0, stream>>>(tmp, bsum, N);
    scan_p2<<<1, 256, 0, stream>>>(bsum, nb, rowptr + N);
    scan_p3<<<nb, 256, 0, stream>>>(tmp, bsum, rowptr, N);

    // ---- CSR build: 2-level counting sort ----
    bcur_init_kernel<<<1, 256, 0, stream>>>(rowptr, bcur, nbuckets, N);
    bin_kernel<<<(E + BIN_CHUNK - 1) / BIN_CHUNK, 256, 0, stream>>>(
        src, dst, bcur, pairs, E, nbuckets);
    bucket_scatter_kernel<<<nbuckets, 256, 0, stream>>>(rowptr, pairs, colsrc, N);

    // ---- layer 1 feature transform (dinv pre-scaled, bf16-packed) ----
    gemm1_kernel<<<(N + 63) / 64, 256, 0, stream>>>(x, W1, dinv, h1b, N);

    // ---- fused pull-aggregation 1 + gemm2 (produces pre-scaled h2s) ----
    l1_kernel<<<(N + 3) / 4, 256, 0, stream>>>(rowptr, colsrc, dinv, h1b, b1, W2, h2s, N);

    // ---- fused pull-aggregation 2 + bias + log_softmax ----
    l2_kernel<<<(N * 16 + 255) / 256, 256, 0, stream>>>(rowptr, colsrc, dinv, h2s, b2, out, N);
}

// Round 6
// 248.374 us; speedup vs baseline: 3.7324x; 1.0096x over previous
//
#include <hip/hip_runtime.h>
#include <math.h>

// GCN, N=50000 nodes, E=800000 edges, F_IN=128, H=128, C=16. f32 in/out; edges int32.
//
// R2: CSR-by-dst pull aggregation (no float atomics), dinv pre-scaling in GEMM
//     epilogues, gemm2 fused into layer-1 pull, log_softmax fused into layer-2.
// R3: 3-phase multi-block scan.
// R4: h1 staged as packed bf16; w2s k-interleave kills 4-way LDS conflict.
// R5: 2-level counting-sort CSR build (killed 17x scatter write amplification).
// R6: latency-bound gathers vectorized: l1 = dwordx4, 16 lanes/row, 4 edges per
//     wave-instruction (4x MLP, 4x fewer addr calcs); l2 = float4, 4 lanes/row,
//     16 edges per instruction, one wave per node (kills loop-length divergence).

#define NBUCKET_SHIFT 8                   // bucket = dst >> 8 (256 nodes/bucket)
#define BIN_CHUNK 4096                    // edges staged per bin block

__device__ __forceinline__ unsigned pack_bf16x2(float a, float b) {
    unsigned ua = __float_as_uint(a), ub = __float_as_uint(b);
    ua = (ua + 0x7fffu + ((ua >> 16) & 1u)) >> 16;   // RNE
    ub = (ub + 0x7fffu + ((ub >> 16) & 1u)) >> 16;
    return (ub << 16) | ua;
}

__device__ __forceinline__ float2 unpack_bf16x2(unsigned u) {
    return make_float2(__uint_as_float(u << 16), __uint_as_float(u & 0xffff0000u));
}

// ---------------- histogram of in-degree (real edges) ----------------
__global__ void hist_kernel(const int* __restrict__ dst, int* __restrict__ cnt, int E) {
    int i = blockIdx.x * blockDim.x + threadIdx.x;
    if (i < E) atomicAdd(&cnt[dst[i]], 1);
}

__global__ void dinv_kernel(const int* __restrict__ cnt, float* __restrict__ dinv, int N) {
    int i = blockIdx.x * blockDim.x + threadIdx.x;
    if (i < N) dinv[i] = rsqrtf((float)cnt[i] + 1.0f);  // +1 self-loop; deg >= 1
}

// ---------------- 3-phase exclusive scan: cnt[N] -> rowptr[N+1] ----------------
__global__ __launch_bounds__(256)
void scan_p1(const int* __restrict__ cnt, int* __restrict__ bsum, int N) {
    __shared__ int sm[256];
    int t = threadIdx.x;
    int i = blockIdx.x * 256 + t;
    sm[t] = (i < N) ? cnt[i] : 0;
    __syncthreads();
#pragma unroll
    for (int off = 128; off >= 1; off >>= 1) {
        if (t < off) sm[t] += sm[t + off];
        __syncthreads();
    }
    if (t == 0) bsum[blockIdx.x] = sm[0];
}

__global__ __launch_bounds__(256)
void scan_p2(int* __restrict__ bsum, int nb, int* __restrict__ rowptrN) {
    __shared__ int sm[256];
    int t = threadIdx.x;
    int v = (t < nb) ? bsum[t] : 0;
    sm[t] = v;
    __syncthreads();
#pragma unroll
    for (int off = 1; off < 256; off <<= 1) {
        int u = (t >= off) ? sm[t - off] : 0;
        __syncthreads();
        sm[t] += u;
        __syncthreads();
    }
    if (t < nb) bsum[t] = sm[t] - v;   // exclusive prefix
    if (t == 255) *rowptrN = sm[255];  // grand total
}

__global__ __launch_bounds__(256)
void scan_p3(const int* __restrict__ cnt, const int* __restrict__ bsum,
             int* __restrict__ rowptr, int N) {
    __shared__ int sm[256];
    int t = threadIdx.x;
    int i = blockIdx.x * 256 + t;
    int v = (i < N) ? cnt[i] : 0;
    sm[t] = v;
    __syncthreads();
#pragma unroll
    for (int off = 1; off < 256; off <<= 1) {
        int u = (t >= off) ? sm[t - off] : 0;
        __syncthreads();
        sm[t] += u;
        __syncthreads();
    }
    if (i < N) rowptr[i] = sm[t] - v + bsum[blockIdx.x];
}

// ---------------- bucket cursor init: bcur[b] = rowptr[b<<8] ----------------
__global__ void bcur_init_kernel(const int* __restrict__ rowptr, int* __restrict__ bcur,
                                 int nbuckets, int N) {
    int b = blockIdx.x * blockDim.x + threadIdx.x;
    if (b < nbuckets) {
        int node = b << NBUCKET_SHIFT;
        bcur[b] = rowptr[node < N ? node : N];
    }
}

// ---------------- phase 1: bin edges into coarse buckets (LDS-staged) ----------
__global__ __launch_bounds__(256)
void bin_kernel(const int* __restrict__ src, const int* __restrict__ dst,
                int* __restrict__ bcur, uint2* __restrict__ pairs, int E, int nbuckets) {
    __shared__ uint2 spair[BIN_CHUNK];   // 32 KB
    __shared__ int bcnt[256];
    __shared__ int bbase[256];
    const int tid = threadIdx.x;
    const int e0 = blockIdx.x * BIN_CHUNK;
    const int cnt = min(BIN_CHUNK, E - e0);

    if (tid < nbuckets) bcnt[tid] = 0;
    __syncthreads();

    for (int i = tid; i < cnt; i += 256) {
        int s = src[e0 + i], d = dst[e0 + i];
        spair[i] = make_uint2((unsigned)s, (unsigned)d);
        atomicAdd(&bcnt[d >> NBUCKET_SHIFT], 1);
    }
    __syncthreads();

    if (tid < nbuckets) {
        int c = bcnt[tid];
        bbase[tid] = (c > 0) ? atomicAdd(&bcur[tid], c) : 0;
        bcnt[tid] = 0;   // reuse as local cursor
    }
    __syncthreads();

    for (int i = tid; i < cnt; i += 256) {
        uint2 p = spair[i];
        int b = (int)(p.y >> NBUCKET_SHIFT);
        int off = atomicAdd(&bcnt[b], 1);
        pairs[bbase[b] + off] = p;
    }
}

// ---------------- phase 2: per-bucket scatter with LDS per-dst cursors --------
__global__ __launch_bounds__(256)
void bucket_scatter_kernel(const int* __restrict__ rowptr, const uint2* __restrict__ pairs,
                           int* __restrict__ colsrc, int N) {
    __shared__ int cur[256];
    const int tid = threadIdx.x;
    const int nb0 = blockIdx.x << NBUCKET_SHIFT;
    const int nodes = min(256, N - nb0);
    if (tid < nodes) cur[tid] = rowptr[nb0 + tid];
    __syncthreads();

    const int lo = rowptr[nb0];
    const int hi = rowptr[(nb0 + 256 < N) ? nb0 + 256 : N];
    for (int i = lo + tid; i < hi; i += 256) {
        uint2 p = pairs[i];
        int pos = atomicAdd(&cur[(int)p.y - nb0], 1);
        colsrc[pos] = (int)p.x;
    }
}

// ---------------- gemm1: h1b[N,128 bf16] = pack((x @ W1) * dinv[row]) ----------------
__global__ __launch_bounds__(256)
void gemm1_kernel(const float* __restrict__ x, const float* __restrict__ W,
                  const float* __restrict__ dinv, unsigned* __restrict__ h1b, int N) {
    __shared__ float xs[64 * 64];     // [row][k]
    __shared__ float wsh[64 * 128];   // [k][col]
    const int tid = threadIdx.x;
    const int row0 = blockIdx.x * 64;
    const int ty = tid >> 5;          // 0..7 -> 8 rows each
    const int tx = tid & 31;          // 0..31 -> 4 cols each

    float acc[8][4];
#pragma unroll
    for (int r = 0; r < 8; r++)
#pragma unroll
        for (int c = 0; c < 4; c++) acc[r][c] = 0.0f;

    for (int kk = 0; kk < 128; kk += 64) {
        const float4* xg = (const float4*)x;
        for (int i = tid; i < 1024; i += 256) {
            int r = i >> 4, k4 = i & 15;
            int row = row0 + r;
            float4 v = make_float4(0.f, 0.f, 0.f, 0.f);
            if (row < N) v = xg[row * 32 + (kk >> 2) + k4];
            ((float4*)xs)[i] = v;
        }
        const float4* wg = (const float4*)W;
        for (int i = tid; i < 2048; i += 256) {
            int r = i >> 5, c4 = i & 31;
            ((float4*)wsh)[i] = wg[(kk + r) * 32 + c4];
        }
        __syncthreads();

#pragma unroll 8
        for (int k = 0; k < 64; k++) {
            float4 wv = ((const float4*)wsh)[k * 32 + tx];
#pragma unroll
            for (int r = 0; r < 8; r++) {
                float xv = xs[(ty * 8 + r) * 64 + k];
                acc[r][0] = fmaf(xv, wv.x, acc[r][0]);
                acc[r][1] = fmaf(xv, wv.y, acc[r][1]);
                acc[r][2] = fmaf(xv, wv.z, acc[r][2]);
                acc[r][3] = fmaf(xv, wv.w, acc[r][3]);
            }
        }
        __syncthreads();
    }

#pragma unroll
    for (int r = 0; r < 8; r++) {
        int row = row0 + ty * 8 + r;
        if (row < N) {
            float dv = dinv[row];
            uint2 p;
            p.x = pack_bf16x2(acc[r][0] * dv, acc[r][1] * dv);
            p.y = pack_bf16x2(acc[r][2] * dv, acc[r][3] * dv);
            ((uint2*)h1b)[row * 32 + tx] = p;
        }
    }
}

// ---------------- fused layer-1 pull + gemm2 ----------------
// One wave per dst node. Lane = edge-group g (lane>>4) x 16B chunk c (lane&15).
// 4 edges gathered per dwordx4 instruction; groups combined via shfl_xor(16,32).
__global__ __launch_bounds__(256)
void l1_kernel(const int* __restrict__ rowptr, const int* __restrict__ colsrc,
               const float* __restrict__ dinv, const unsigned* __restrict__ h1b,
               const float* __restrict__ b1, const float* __restrict__ W2,
               float* __restrict__ h2s, int N) {
    __shared__ float w2s[128 * 16];   // [k][c], 8 KB
    __shared__ float rows[4][128];    // 2 KB
    const int tid = threadIdx.x;
    for (int i = tid; i < 512; i += 256)
        ((float4*)w2s)[i] = ((const float4*)W2)[i];

    const int wave = tid >> 6, lane = tid & 63;
    const int g = lane >> 4;          // edge group 0..3
    const int c = lane & 15;          // 16B chunk (8 feats)
    const int d = blockIdx.x * 4 + wave;
    const uint4* h1q = (const uint4*)h1b;   // row = 16 uint4

    if (d < N) {
        float a[8];
#pragma unroll
        for (int j = 0; j < 8; j++) a[j] = 0.0f;

        if (g == 0) {                 // self-loop term, group 0 only
            uint4 v = h1q[d * 16 + c];
            float2 t;
            t = unpack_bf16x2(v.x); a[0] += t.x; a[1] += t.y;
            t = unpack_bf16x2(v.y); a[2] += t.x; a[3] += t.y;
            t = unpack_bf16x2(v.z); a[4] += t.x; a[5] += t.y;
            t = unpack_bf16x2(v.w); a[6] += t.x; a[7] += t.y;
        }

        int i = rowptr[d], end = rowptr[d + 1];
        for (; i + 8 <= end; i += 8) {    // 8 edges (2 gathers) in flight
            int sA = colsrc[i + g], sB = colsrc[i + 4 + g];
            uint4 vA = h1q[sA * 16 + c];
            uint4 vB = h1q[sB * 16 + c];
            float2 t;
            t = unpack_bf16x2(vA.x); a[0] += t.x; a[1] += t.y;
            t = unpack_bf16x2(vA.y); a[2] += t.x; a[3] += t.y;
            t = unpack_bf16x2(vA.z); a[4] += t.x; a[5] += t.y;
            t = unpack_bf16x2(vA.w); a[6] += t.x; a[7] += t.y;
            t = unpack_bf16x2(vB.x); a[0] += t.x; a[1] += t.y;
            t = unpack_bf16x2(vB.y); a[2] += t.x; a[3] += t.y;
            t = unpack_bf16x2(vB.z); a[4] += t.x; a[5] += t.y;
            t = unpack_bf16x2(vB.w); a[6] += t.x; a[7] += t.y;
        }
        for (; i + 4 <= end; i += 4) {
            int s = colsrc[i + g];
            uint4 v = h1q[s * 16 + c];
            float2 t;
            t = unpack_bf16x2(v.x); a[0] += t.x; a[1] += t.y;
            t = unpack_bf16x2(v.y); a[2] += t.x; a[3] += t.y;
            t = unpack_bf16x2(v.z); a[4] += t.x; a[5] += t.y;
            t = unpack_bf16x2(v.w); a[6] += t.x; a[7] += t.y;
        }
        if (i < end && g < end - i) {     // tail (<4 edges), masked by group
            int s = colsrc[i + g];
            uint4 v = h1q[s * 16 + c];
            float2 t;
            t = unpack_bf16x2(v.x); a[0] += t.x; a[1] += t.y;
            t = unpack_bf16x2(v.y); a[2] += t.x; a[3] += t.y;
            t = unpack_bf16x2(v.z); a[4] += t.x; a[5] += t.y;
            t = unpack_bf16x2(v.w); a[6] += t.x; a[7] += t.y;
        }

        // combine the 4 edge groups
#pragma unroll
        for (int j = 0; j < 8; j++) {
            a[j] += __shfl_xor(a[j], 16, 64);
            a[j] += __shfl_xor(a[j], 32, 64);
        }

        float dv = dinv[d];
        float4 bA = ((const float4*)b1)[2 * c];
        float4 bB = ((const float4*)b1)[2 * c + 1];
        a[0] = fmaxf(a[0] * dv + bA.x, 0.f);
        a[1] = fmaxf(a[1] * dv + bA.y, 0.f);
        a[2] = fmaxf(a[2] * dv + bA.z, 0.f);
        a[3] = fmaxf(a[3] * dv + bA.w, 0.f);
        a[4] = fmaxf(a[4] * dv + bB.x, 0.f);
        a[5] = fmaxf(a[5] * dv + bB.y, 0.f);
        a[6] = fmaxf(a[6] * dv + bB.z, 0.f);
        a[7] = fmaxf(a[7] * dv + bB.w, 0.f);
        if (g == 0) {
            ((float4*)&rows[wave][0])[2 * c]     = make_float4(a[0], a[1], a[2], a[3]);
            ((float4*)&rows[wave][0])[2 * c + 1] = make_float4(a[4], a[5], a[6], a[7]);
        }
    }
    __syncthreads();
    if (d < N) {
        int cc = lane & 15, kg = lane >> 4;
        float p = 0.0f;
        // kk = 4k+kg interleave: 2-way LDS aliasing only (free per m136).
#pragma unroll
        for (int k = 0; k < 32; k++) {
            int kk = 4 * k + kg;
            p = fmaf(rows[wave][kk], w2s[kk * 16 + cc], p);
        }
        p += __shfl_xor(p, 16, 64);
        p += __shfl_xor(p, 32, 64);
        if (kg == 0) h2s[d * 16 + cc] = p * dinv[d];
    }
}

// ---------------- fused layer-2 pull + log_softmax ----------------
// One wave per node. Lane = edge-group g (lane>>2) x float4 chunk c (lane&3).
// 16 edges gathered per instruction; combine via shfl_xor(4,8,16,32).
__global__ __launch_bounds__(256)
void l2_kernel(const int* __restrict__ rowptr, const int* __restrict__ colsrc,
               const float* __restrict__ dinv, const float* __restrict__ h2s,
               const float* __restrict__ b2, float* __restrict__ out, int N) {
    const int tid = threadIdx.x;
    const int wave = tid >> 6, lane = tid & 63;
    const int g = lane >> 2;          // edge group 0..15
    const int c = lane & 3;           // float4 chunk (4 feats)
    const int d = blockIdx.x * 4 + wave;
    if (d >= N) return;
    const float4* h2q = (const float4*)h2s;  // row = 4 float4

    float4 acc = make_float4(0.f, 0.f, 0.f, 0.f);
    if (g == 0) acc = h2q[d * 4 + c];        // self-loop term
    int i = rowptr[d], end = rowptr[d + 1];
    for (; i + 16 <= end; i += 16) {
        int s = colsrc[i + g];
        float4 v = h2q[s * 4 + c];
        acc.x += v.x; acc.y += v.y; acc.z += v.z; acc.w += v.w;
    }
    if (i < end && g < end - i) {            // tail (<16 edges), masked
        int s = colsrc[i + g];
        float4 v = h2q[s * 4 + c];
        acc.x += v.x; acc.y += v.y; acc.z += v.z; acc.w += v.w;
    }
#pragma unroll
    for (int off = 4; off <= 32; off <<= 1) {
        acc.x += __shfl_xor(acc.x, off, 64);
        acc.y += __shfl_xor(acc.y, off, 64);
        acc.z += __shfl_xor(acc.z, off, 64);
        acc.w += __shfl_xor(acc.w, off, 64);
    }
    float dv = dinv[d];
    float4 b = ((const float4*)b2)[c];
    float4 val = make_float4(acc.x * dv + b.x, acc.y * dv + b.y,
                             acc.z * dv + b.z, acc.w * dv + b.w);
    float m = fmaxf(fmaxf(val.x, val.y), fmaxf(val.z, val.w));
    m = fmaxf(m, __shfl_xor(m, 1, 64));
    m = fmaxf(m, __shfl_xor(m, 2, 64));
    float e = expf(val.x - m) + expf(val.y - m) + expf(val.z - m) + expf(val.w - m);
    e += __shfl_xor(e, 1, 64);
    e += __shfl_xor(e, 2, 64);
    float lse = m + logf(e);
    if (g == 0)
        ((float4*)out)[d * 4 + c] =
            make_float4(val.x - lse, val.y - lse, val.z - lse, val.w - lse);
}

extern "C" void kernel_launch(void* const* d_in, const int* in_sizes, int n_in,
                              void* d_out, int out_size, void* d_ws, size_t ws_size,
                              hipStream_t stream) {
    const float* x  = (const float*)d_in[0];
    const int*  ei  = (const int*)d_in[1];
    const float* W1 = (const float*)d_in[2];
    const float* b1 = (const float*)d_in[3];
    const float* W2 = (const float*)d_in[4];
    const float* b2 = (const float*)d_in[5];
    float* out = (float*)d_out;

    const int N = in_sizes[0] / 128;   // 50000
    const int E = in_sizes[1] / 2;     // 800000
    const int* src = ei;
    const int* dst = ei + E;
    const int nbuckets = (N + 255) >> NBUCKET_SHIFT;   // 196 (<= 256 required)

    // Workspace layout:
    //   dinv   : N floats
    //   tmp    : N ints (histogram)
    //   rowptr : N+4 ints
    //   bsum   : 256 ints
    //   bcur   : 256 ints (bucket cursors)
    //   colsrc : E ints
    //   pairs  : E uint2 (6.4 MB)
    //   h1b    : N*64 uints (12.8 MB, packed bf16x2)
    //   h2s    : N*16 floats (3.2 MB)      total ~26 MB
    float*    wsf    = (float*)d_ws;
    float*    dinv   = wsf;
    int*      tmp    = (int*)(wsf + N);
    int*      rowptr = tmp + N;
    int*      bsum   = rowptr + N + 4;
    int*      bcur   = bsum + 256;
    int*      colsrc = bcur + 256;
    uint2*    pairs  = (uint2*)(colsrc + E);
    unsigned* h1b    = (unsigned*)(pairs + E);
    float*    h2s    = (float*)(h1b + (size_t)N * 64);

    const int nb = (N + 255) / 256;    // 196 scan blocks

    // ---- degree + rowptr ----
    hipMemsetAsync(tmp, 0, (size_t)N * sizeof(int), stream);
    hist_kernel<<<(E + 255) / 256, 256, 0, stream>>>(dst, tmp, E);
    dinv_kernel<<<(N + 255) / 256, 256, 0, stream>>>(tmp, dinv, N);
    scan_p1<<<nb, 256, 0, stream>>>(tmp, bsum, N);
    scan_p2<<<1, 256, 0, stream>>>(bsum, nb, rowptr + N);
    scan_p3<<<nb, 256, 0, stream>>>(tmp, bsum, rowptr, N);

    // ---- CSR build: 2-level counting sort ----
    bcur_init_kernel<<<1, 256, 0, stream>>>(rowptr, bcur, nbuckets, N);
    bin_kernel<<<(E + BIN_CHUNK - 1) / BIN_CHUNK, 256, 0, stream>>>(
        src, dst, bcur, pairs, E, nbuckets);
    bucket_scatter_kernel<<<nbuckets, 256, 0, stream>>>(rowptr, pairs, colsrc, N);

    // ---- layer 1 feature transform (dinv pre-scaled, bf16-packed) ----
    gemm1_kernel<<<(N + 63) / 64, 256, 0, stream>>>(x, W1, dinv, h1b, N);

    // ---- fused pull-aggregation 1 + gemm2 (produces pre-scaled h2s) ----
    l1_kernel<<<(N + 3) / 4, 256, 0, stream>>>(rowptr, colsrc, dinv, h1b, b1, W2, h2s, N);

    // ---- fused pull-aggregation 2 + bias + log_softmax ----
    l2_kernel<<<(N + 3) / 4, 256, 0, stream>>>(rowptr, colsrc, dinv, h2s, b2, out, N);
}

// Round 7
// 240.360 us; speedup vs baseline: 3.8568x; 1.0333x over previous
//
#include <hip/hip_runtime.h>
#include <math.h>

// GCN, N=50000 nodes, E=800000 edges, F_IN=128, H=128, C=16. f32 in/out; edges int32.
//
// R2: CSR-by-dst pull aggregation (no float atomics), dinv pre-scaling.
// R3: multi-block scan. R4: bf16 h1 staging. R5: counting-sort CSR build.
// R6: vectorized gathers (16B/lane), wave-per-node layouts.
// R7: (a) layer-1 gather split into 4 feature-slice passes, slice-major h1b
//     (3.2 MB/slice < 4 MB per-XCD L2 -> gathers become L2 hits; FETCH was
//     111 MB for a 12.8 MB array). gemm2 unfused back to its own kernel.
//     (b) CSR build reorganized: LDS bucket histogram + bucket scan + bin +
//     one bucket_build kernel (rowptr+dinv+colsrc); kills the 800k-global-
//     atomic histogram and 4 helper kernels.

#define NBUCKET_SHIFT 8                   // bucket = dst >> 8 (256 nodes/bucket)
#define BIN_CHUNK 4096                    // edges per binning block

__device__ __forceinline__ unsigned pack_bf16x2(float a, float b) {
    unsigned ua = __float_as_uint(a), ub = __float_as_uint(b);
    ua = (ua + 0x7fffu + ((ua >> 16) & 1u)) >> 16;   // RNE
    ub = (ub + 0x7fffu + ((ub >> 16) & 1u)) >> 16;
    return (ub << 16) | ua;
}

__device__ __forceinline__ float2 unpack_bf16x2(unsigned u) {
    return make_float2(__uint_as_float(u << 16), __uint_as_float(u & 0xffff0000u));
}

// ---------------- CSR build phase 1: per-bucket edge counts (LDS-staged) ------
__global__ __launch_bounds__(256)
void bucket_count_kernel(const int* __restrict__ dst, int* __restrict__ bktcnt,
                         int E, int nbuckets) {
    __shared__ int cnt[256];
    const int tid = threadIdx.x;
    cnt[tid] = 0;
    __syncthreads();
    const int e0 = blockIdx.x * BIN_CHUNK;
    const int n = min(BIN_CHUNK, E - e0);
    for (int i = tid; i < n; i += 256)
        atomicAdd(&cnt[dst[e0 + i] >> NBUCKET_SHIFT], 1);
    __syncthreads();
    if (tid < nbuckets && cnt[tid] > 0) atomicAdd(&bktcnt[tid], cnt[tid]);
}

// ---------------- phase 2: scan bucket counts -> bktbase, seed bin cursors ----
__global__ __launch_bounds__(256)
void bucket_scan_kernel(const int* __restrict__ bktcnt, int* __restrict__ bktbase,
                        int* __restrict__ bcur, int* __restrict__ rowptrN,
                        int nbuckets, int E) {
    __shared__ int sm[256];
    const int t = threadIdx.x;
    int v = (t < nbuckets) ? bktcnt[t] : 0;
    sm[t] = v;
    __syncthreads();
#pragma unroll
    for (int off = 1; off < 256; off <<= 1) {
        int u = (t >= off) ? sm[t - off] : 0;
        __syncthreads();
        sm[t] += u;
        __syncthreads();
    }
    int excl = sm[t] - v;
    if (t < nbuckets) { bktbase[t] = excl; bcur[t] = excl; }
    if (t == nbuckets - 1) bktbase[nbuckets] = excl + v;   // == E
    if (t == 0) *rowptrN = E;
}

// ---------------- phase 3: bin edges into bucket-major pair array -------------
__global__ __launch_bounds__(256)
void bin_kernel(const int* __restrict__ src, const int* __restrict__ dst,
                int* __restrict__ bcur, uint2* __restrict__ pairs, int E, int nbuckets) {
    __shared__ uint2 spair[BIN_CHUNK];   // 32 KB
    __shared__ int bcnt[256];
    __shared__ int bbase[256];
    const int tid = threadIdx.x;
    const int e0 = blockIdx.x * BIN_CHUNK;
    const int cnt = min(BIN_CHUNK, E - e0);

    if (tid < nbuckets) bcnt[tid] = 0;
    __syncthreads();

    for (int i = tid; i < cnt; i += 256) {
        int s = src[e0 + i], d = dst[e0 + i];
        spair[i] = make_uint2((unsigned)s, (unsigned)d);
        atomicAdd(&bcnt[d >> NBUCKET_SHIFT], 1);
    }
    __syncthreads();

    if (tid < nbuckets) {
        int c = bcnt[tid];
        bbase[tid] = (c > 0) ? atomicAdd(&bcur[tid], c) : 0;
        bcnt[tid] = 0;   // reuse as local cursor
    }
    __syncthreads();

    for (int i = tid; i < cnt; i += 256) {
        uint2 p = spair[i];
        int b = (int)(p.y >> NBUCKET_SHIFT);
        int off = atomicAdd(&bcnt[b], 1);
        pairs[bbase[b] + off] = p;
    }
}

// ---------------- phase 4: per-bucket rowptr + dinv + colsrc ------------------
// One block per bucket: LDS histogram of the 256 local dsts, LDS scan ->
// rowptr and dinv, then LDS-cursor scatter of src into colsrc.
__global__ __launch_bounds__(256)
void bucket_build_kernel(const int* __restrict__ bktbase, const uint2* __restrict__ pairs,
                         int* __restrict__ rowptr, float* __restrict__ dinv,
                         int* __restrict__ colsrc, int N) {
    __shared__ int cnt[256];
    __shared__ int sm[256];
    const int tid = threadIdx.x;
    const int nb0 = blockIdx.x << NBUCKET_SHIFT;
    const int lo = bktbase[blockIdx.x], hi = bktbase[blockIdx.x + 1];

    cnt[tid] = 0;
    __syncthreads();
    for (int i = lo + tid; i < hi; i += 256)
        atomicAdd(&cnt[(int)pairs[i].y - nb0], 1);
    __syncthreads();

    int v = cnt[tid];
    sm[tid] = v;
    __syncthreads();
#pragma unroll
    for (int off = 1; off < 256; off <<= 1) {
        int u = (tid >= off) ? sm[tid - off] : 0;
        __syncthreads();
        sm[tid] += u;
        __syncthreads();
    }
    int excl = sm[tid] - v;
    int node = nb0 + tid;
    if (node < N) {
        rowptr[node] = lo + excl;
        dinv[node] = rsqrtf((float)v + 1.0f);   // +1 self-loop
    }
    __syncthreads();
    cnt[tid] = lo + excl;   // reuse as scatter cursor
    __syncthreads();
    for (int i = lo + tid; i < hi; i += 256) {
        uint2 p = pairs[i];
        int pos = atomicAdd(&cnt[(int)p.y - nb0], 1);
        colsrc[pos] = (int)p.x;
    }
}

// ---------------- gemm1: h1b (slice-major bf16) = pack((x @ W1) * dinv[row]) --
// h1b layout: slice s (32 cols) -> N rows -> 16 uints (64 B) per row.
__global__ __launch_bounds__(256)
void gemm1_kernel(const float* __restrict__ x, const float* __restrict__ W,
                  const float* __restrict__ dinv, unsigned* __restrict__ h1b, int N) {
    __shared__ float xs[64 * 64];     // [row][k]
    __shared__ float wsh[64 * 128];   // [k][col]
    const int tid = threadIdx.x;
    const int row0 = blockIdx.x * 64;
    const int ty = tid >> 5;          // 0..7 -> 8 rows each
    const int tx = tid & 31;          // 0..31 -> 4 cols each (cols 4tx..4tx+3)

    float acc[8][4];
#pragma unroll
    for (int r = 0; r < 8; r++)
#pragma unroll
        for (int c = 0; c < 4; c++) acc[r][c] = 0.0f;

    for (int kk = 0; kk < 128; kk += 64) {
        const float4* xg = (const float4*)x;
        for (int i = tid; i < 1024; i += 256) {
            int r = i >> 4, k4 = i & 15;
            int row = row0 + r;
            float4 v = make_float4(0.f, 0.f, 0.f, 0.f);
            if (row < N) v = xg[row * 32 + (kk >> 2) + k4];
            ((float4*)xs)[i] = v;
        }
        const float4* wg = (const float4*)W;
        for (int i = tid; i < 2048; i += 256) {
            int r = i >> 5, c4 = i & 31;
            ((float4*)wsh)[i] = wg[(kk + r) * 32 + c4];
        }
        __syncthreads();

#pragma unroll 8
        for (int k = 0; k < 64; k++) {
            float4 wv = ((const float4*)wsh)[k * 32 + tx];
#pragma unroll
            for (int r = 0; r < 8; r++) {
                float xv = xs[(ty * 8 + r) * 64 + k];
                acc[r][0] = fmaf(xv, wv.x, acc[r][0]);
                acc[r][1] = fmaf(xv, wv.y, acc[r][1]);
                acc[r][2] = fmaf(xv, wv.z, acc[r][2]);
                acc[r][3] = fmaf(xv, wv.w, acc[r][3]);
            }
        }
        __syncthreads();
    }

    const int s = tx >> 3;            // slice of this thread's 4 cols
    const int q = tx & 7;             // uint2 index within slice row
#pragma unroll
    for (int r = 0; r < 8; r++) {
        int row = row0 + ty * 8 + r;
        if (row < N) {
            float dv = dinv[row];
            uint2 p;
            p.x = pack_bf16x2(acc[r][0] * dv, acc[r][1] * dv);
            p.y = pack_bf16x2(acc[r][2] * dv, acc[r][3] * dv);
            ((uint2*)h1b)[(size_t)s * N * 8 + (size_t)row * 8 + q] = p;
        }
    }
}

// ---------------- layer-1 pull, one 32-feature slice ----------------
// Wave = 4 nodes x 4 edge-groups x 4 uint4-chunks. 16 edges per gather instr.
// agg_s[d][0..31] = self + sum_in h1b_s[src]  (all dinv[src]-prescaled).
__global__ __launch_bounds__(256)
void l1_pass_kernel(const int* __restrict__ rowptr, const int* __restrict__ colsrc,
                    const unsigned* __restrict__ h1b_s, float* __restrict__ agg_s, int N) {
    const int tid = threadIdx.x;
    const int wave = tid >> 6, lane = tid & 63;
    const int n = lane >> 4;          // node 0..3 within wave
    const int g = (lane >> 2) & 3;    // edge group 0..3
    const int c = lane & 3;           // uint4 chunk 0..3
    const int d = blockIdx.x * 16 + wave * 4 + n;
    if (d >= N) return;
    const uint4* hq = (const uint4*)h1b_s;   // node row = 4 uint4

    float a[8];
#pragma unroll
    for (int j = 0; j < 8; j++) a[j] = 0.0f;

    if (g == 0) {                     // self-loop term
        uint4 v = hq[(size_t)d * 4 + c];
        float2 t;
        t = unpack_bf16x2(v.x); a[0] += t.x; a[1] += t.y;
        t = unpack_bf16x2(v.y); a[2] += t.x; a[3] += t.y;
        t = unpack_bf16x2(v.z); a[4] += t.x; a[5] += t.y;
        t = unpack_bf16x2(v.w); a[6] += t.x; a[7] += t.y;
    }

    int i = rowptr[d], end = rowptr[d + 1];
    for (; i + 8 <= end; i += 8) {    // 8 edges, 2 gathers in flight
        int sA = colsrc[i + g], sB = colsrc[i + 4 + g];
        uint4 vA = hq[(size_t)sA * 4 + c];
        uint4 vB = hq[(size_t)sB * 4 + c];
        float2 t;
        t = unpack_bf16x2(vA.x); a[0] += t.x; a[1] += t.y;
        t = unpack_bf16x2(vA.y); a[2] += t.x; a[3] += t.y;
        t = unpack_bf16x2(vA.z); a[4] += t.x; a[5] += t.y;
        t = unpack_bf16x2(vA.w); a[6] += t.x; a[7] += t.y;
        t = unpack_bf16x2(vB.x); a[0] += t.x; a[1] += t.y;
        t = unpack_bf16x2(vB.y); a[2] += t.x; a[3] += t.y;
        t = unpack_bf16x2(vB.z); a[4] += t.x; a[5] += t.y;
        t = unpack_bf16x2(vB.w); a[6] += t.x; a[7] += t.y;
    }
    for (; i + 4 <= end; i += 4) {
        int sx = colsrc[i + g];
        uint4 v = hq[(size_t)sx * 4 + c];
        float2 t;
        t = unpack_bf16x2(v.x); a[0] += t.x; a[1] += t.y;
        t = unpack_bf16x2(v.y); a[2] += t.x; a[3] += t.y;
        t = unpack_bf16x2(v.z); a[4] += t.x; a[5] += t.y;
        t = unpack_bf16x2(v.w); a[6] += t.x; a[7] += t.y;
    }
    if (i < end && g < end - i) {     // tail (<4 edges)
        int sx = colsrc[i + g];
        uint4 v = hq[(size_t)sx * 4 + c];
        float2 t;
        t = unpack_bf16x2(v.x); a[0] += t.x; a[1] += t.y;
        t = unpack_bf16x2(v.y); a[2] += t.x; a[3] += t.y;
        t = unpack_bf16x2(v.z); a[4] += t.x; a[5] += t.y;
        t = unpack_bf16x2(v.w); a[6] += t.x; a[7] += t.y;
    }

#pragma unroll
    for (int j = 0; j < 8; j++) {     // combine 4 edge groups (within 16-lane node)
        a[j] += __shfl_xor(a[j], 4, 64);
        a[j] += __shfl_xor(a[j], 8, 64);
    }
    if (g == 0) {
        ((float4*)agg_s)[(size_t)d * 8 + c * 2] = make_float4(a[0], a[1], a[2], a[3]);
        ((float4*)agg_s)[(size_t)d * 8 + c * 2 + 1] = make_float4(a[4], a[5], a[6], a[7]);
    }
}

// ---------------- gemm2: h2s[N,16] = dinv * (relu(dinv*agg + b1) @ W2) --------
// agg is slice-major: slice s base = agg + s*N*32. 16 rows/block.
__global__ __launch_bounds__(256)
void gemm2_kernel(const float* __restrict__ agg, const float* __restrict__ dinv,
                  const float* __restrict__ b1, const float* __restrict__ W2,
                  float* __restrict__ h2s, int N) {
    __shared__ float hs[16 * 128];
    __shared__ float w2s[128 * 16];
    const int tid = threadIdx.x;
    const int row0 = blockIdx.x * 16;

    for (int i = tid; i < 512; i += 256)
        ((float4*)w2s)[i] = ((const float4*)W2)[i];

    for (int i = tid; i < 512; i += 256) {
        int r = i >> 5, q = i & 31;           // q = float4 index within 128-col row
        int row = row0 + r;
        float4 v = make_float4(0.f, 0.f, 0.f, 0.f);
        if (row < N) {
            int s = q >> 3, qq = q & 7;
            v = ((const float4*)agg)[(size_t)s * N * 8 + (size_t)row * 8 + qq];
            float dv = dinv[row];
            float4 b = ((const float4*)b1)[q];
            v.x = fmaxf(v.x * dv + b.x, 0.f);
            v.y = fmaxf(v.y * dv + b.y, 0.f);
            v.z = fmaxf(v.z * dv + b.z, 0.f);
            v.w = fmaxf(v.w * dv + b.w, 0.f);
        }
        ((float4*)hs)[i] = v;
    }
    __syncthreads();

    int r = tid >> 4, c = tid & 15;
    float acc = 0.0f;
#pragma unroll 16
    for (int k = 0; k < 128; k++)
        acc = fmaf(hs[r * 128 + k], w2s[k * 16 + c], acc);

    int row = row0 + r;
    if (row < N) h2s[row * 16 + c] = acc * dinv[row];   // pre-scale for layer 2
}

// ---------------- fused layer-2 pull + log_softmax ----------------
// One wave per node. Lane = edge-group g (lane>>2) x float4 chunk c (lane&3).
__global__ __launch_bounds__(256)
void l2_kernel(const int* __restrict__ rowptr, const int* __restrict__ colsrc,
               const float* __restrict__ dinv, const float* __restrict__ h2s,
               const float* __restrict__ b2, float* __restrict__ out, int N) {
    const int tid = threadIdx.x;
    const int wave = tid >> 6, lane = tid & 63;
    const int g = lane >> 2;          // edge group 0..15
    const int c = lane & 3;           // float4 chunk (4 feats)
    const int d = blockIdx.x * 4 + wave;
    if (d >= N) return;
    const float4* h2q = (const float4*)h2s;  // row = 4 float4

    float4 acc = make_float4(0.f, 0.f, 0.f, 0.f);
    if (g == 0) acc = h2q[d * 4 + c];        // self-loop term
    int i = rowptr[d], end = rowptr[d + 1];
    for (; i + 16 <= end; i += 16) {
        int s = colsrc[i + g];
        float4 v = h2q[s * 4 + c];
        acc.x += v.x; acc.y += v.y; acc.z += v.z; acc.w += v.w;
    }
    if (i < end && g < end - i) {            // tail (<16 edges)
        int s = colsrc[i + g];
        float4 v = h2q[s * 4 + c];
        acc.x += v.x; acc.y += v.y; acc.z += v.z; acc.w += v.w;
    }
#pragma unroll
    for (int off = 4; off <= 32; off <<= 1) {
        acc.x += __shfl_xor(acc.x, off, 64);
        acc.y += __shfl_xor(acc.y, off, 64);
        acc.z += __shfl_xor(acc.z, off, 64);
        acc.w += __shfl_xor(acc.w, off, 64);
    }
    float dv = dinv[d];
    float4 b = ((const float4*)b2)[c];
    float4 val = make_float4(acc.x * dv + b.x, acc.y * dv + b.y,
                             acc.z * dv + b.z, acc.w * dv + b.w);
    float m = fmaxf(fmaxf(val.x, val.y), fmaxf(val.z, val.w));
    m = fmaxf(m, __shfl_xor(m, 1, 64));
    m = fmaxf(m, __shfl_xor(m, 2, 64));
    float e = expf(val.x - m) + expf(val.y - m) + expf(val.z - m) + expf(val.w - m);
    e += __shfl_xor(e, 1, 64);
    e += __shfl_xor(e, 2, 64);
    float lse = m + logf(e);
    if (g == 0)
        ((float4*)out)[d * 4 + c] =
            make_float4(val.x - lse, val.y - lse, val.z - lse, val.w - lse);
}

extern "C" void kernel_launch(void* const* d_in, const int* in_sizes, int n_in,
                              void* d_out, int out_size, void* d_ws, size_t ws_size,
                              hipStream_t stream) {
    const float* x  = (const float*)d_in[0];
    const int*  ei  = (const int*)d_in[1];
    const float* W1 = (const float*)d_in[2];
    const float* b1 = (const float*)d_in[3];
    const float* W2 = (const float*)d_in[4];
    const float* b2 = (const float*)d_in[5];
    float* out = (float*)d_out;

    const int N = in_sizes[0] / 128;   // 50000
    const int E = in_sizes[1] / 2;     // 800000
    const int* src = ei;
    const int* dst = ei + E;
    const int nbuckets = (N + 255) >> NBUCKET_SHIFT;   // 196 (< 256 required)
    const int nbins = (E + BIN_CHUNK - 1) / BIN_CHUNK; // 196

    // Workspace layout (ints/floats are 4 B; all offsets even -> uint2 8B-aligned):
    //   dinv    : N floats
    //   rowptr  : N+4 ints
    //   bktcnt  : 256 ints
    //   bktbase : 260 ints
    //   bcur    : 256 ints
    //   colsrc  : E ints (3.2 MB)
    //   pairs   : E uint2 (6.4 MB)  -- dead after bucket_build; agg overlays it
    //   agg     : N*128 floats (25.6 MB, slice-major 4 x N*32) at pairs base
    //   h1b     : N*64 uints (12.8 MB, slice-major 4 x N*16)
    //   h2s     : N*16 floats (3.2 MB)        peak ~45 MB
    float*    wsf     = (float*)d_ws;
    float*    dinv    = wsf;
    int*      rowptr  = (int*)(wsf + N);
    int*      bktcnt  = rowptr + N + 4;
    int*      bktbase = bktcnt + 256;
    int*      bcur    = bktbase + 260;
    int*      colsrc  = bcur + 256;
    uint2*    pairs   = (uint2*)(colsrc + E);
    float*    agg     = (float*)pairs;                    // overlays pairs
    unsigned* h1b     = (unsigned*)(agg + (size_t)N * 128);
    float*    h2s     = (float*)(h1b + (size_t)N * 64);

    // ---- CSR build ----
    hipMemsetAsync(bktcnt, 0, 256 * sizeof(int), stream);
    bucket_count_kernel<<<nbins, 256, 0, stream>>>(dst, bktcnt, E, nbuckets);
    bucket_scan_kernel<<<1, 256, 0, stream>>>(bktcnt, bktbase, bcur, rowptr + N,
                                              nbuckets, E);
    bin_kernel<<<nbins, 256, 0, stream>>>(src, dst, bcur, pairs, E, nbuckets);
    bucket_build_kernel<<<nbuckets, 256, 0, stream>>>(bktbase, pairs, rowptr,
                                                      dinv, colsrc, N);

    // ---- layer 1 feature transform (dinv pre-scaled, bf16, slice-major) ----
    gemm1_kernel<<<(N + 63) / 64, 256, 0, stream>>>(x, W1, dinv, h1b, N);

    // ---- layer-1 pull, 4 L2-resident slice passes (pairs now dead -> agg) ----
    {
        int blocks = (N + 15) / 16;
        for (int s = 0; s < 4; s++)
            l1_pass_kernel<<<blocks, 256, 0, stream>>>(
                rowptr, colsrc, h1b + (size_t)s * N * 16, agg + (size_t)s * N * 32, N);
    }

    // ---- gemm2 (+bias/relu, pre-scale) ----
    gemm2_kernel<<<(N + 15) / 16, 256, 0, stream>>>(agg, dinv, b1, W2, h2s, N);

    // ---- fused pull-aggregation 2 + bias + log_softmax ----
    l2_kernel<<<(N + 3) / 4, 256, 0, stream>>>(rowptr, colsrc, dinv, h2s, b2, out, N);
}

// Round 8
// 229.033 us; speedup vs baseline: 4.0475x; 1.0495x over previous
//
#include <hip/hip_runtime.h>
#include <math.h>

// GCN, N=50000 nodes, E=800000 edges, F_IN=128, H=128, C=16. f32 in/out; edges int32.
//
// R2: CSR-by-dst pull aggregation (no float atomics), dinv pre-scaling.
// R3: multi-block scan. R4: bf16 h1 staging. R5: counting-sort CSR build.
// R6: vectorized gathers. R7: 4 L2-resident feature-slice passes for l1;
//     LDS-histogram CSR build.
// R8: gemm1 -> MFMA 16x16x32 bf16 with hi/lo split-A (x = xh + xl, both bf16;
//     two MFMA chains into one accumulator => ~fp32 input accuracy, only W's
//     bf16 rounding remains). W1 pre-packed to bf16 Wt[n][k] (32 KB, L1-hot).
//     Old fp32 vector gemm1 was 45 us at 14% occupancy, MfmaUtil=0.

#define NBUCKET_SHIFT 8                   // bucket = dst >> 8 (256 nodes/bucket)
#define BIN_CHUNK 4096                    // edges per binning block

typedef __bf16 bf16x8 __attribute__((ext_vector_type(8)));
typedef float  f32x4  __attribute__((ext_vector_type(4)));

__device__ __forceinline__ unsigned short pack_bf16(float f) {
    unsigned u = __float_as_uint(f);
    return (unsigned short)((u + 0x7fffu + ((u >> 16) & 1u)) >> 16);   // RNE
}

__device__ __forceinline__ unsigned pack_bf16x2(float a, float b) {
    return ((unsigned)pack_bf16(b) << 16) | pack_bf16(a);
}

__device__ __forceinline__ float2 unpack_bf16x2(unsigned u) {
    return make_float2(__uint_as_float(u << 16), __uint_as_float(u & 0xffff0000u));
}

// ---------------- CSR build phase 1: per-bucket edge counts (LDS-staged) ------
__global__ __launch_bounds__(256)
void bucket_count_kernel(const int* __restrict__ dst, int* __restrict__ bktcnt,
                         int E, int nbuckets) {
    __shared__ int cnt[256];
    const int tid = threadIdx.x;
    cnt[tid] = 0;
    __syncthreads();
    const int e0 = blockIdx.x * BIN_CHUNK;
    const int n = min(BIN_CHUNK, E - e0);
    for (int i = tid; i < n; i += 256)
        atomicAdd(&cnt[dst[e0 + i] >> NBUCKET_SHIFT], 1);
    __syncthreads();
    if (tid < nbuckets && cnt[tid] > 0) atomicAdd(&bktcnt[tid], cnt[tid]);
}

// ---------------- phase 2: scan bucket counts -> bktbase, seed bin cursors ----
__global__ __launch_bounds__(256)
void bucket_scan_kernel(const int* __restrict__ bktcnt, int* __restrict__ bktbase,
                        int* __restrict__ bcur, int* __restrict__ rowptrN,
                        int nbuckets, int E) {
    __shared__ int sm[256];
    const int t = threadIdx.x;
    int v = (t < nbuckets) ? bktcnt[t] : 0;
    sm[t] = v;
    __syncthreads();
#pragma unroll
    for (int off = 1; off < 256; off <<= 1) {
        int u = (t >= off) ? sm[t - off] : 0;
        __syncthreads();
        sm[t] += u;
        __syncthreads();
    }
    int excl = sm[t] - v;
    if (t < nbuckets) { bktbase[t] = excl; bcur[t] = excl; }
    if (t == nbuckets - 1) bktbase[nbuckets] = excl + v;   // == E
    if (t == 0) *rowptrN = E;
}

// ---------------- phase 3: bin edges into bucket-major pair array -------------
__global__ __launch_bounds__(256)
void bin_kernel(const int* __restrict__ src, const int* __restrict__ dst,
                int* __restrict__ bcur, uint2* __restrict__ pairs, int E, int nbuckets) {
    __shared__ uint2 spair[BIN_CHUNK];   // 32 KB
    __shared__ int bcnt[256];
    __shared__ int bbase[256];
    const int tid = threadIdx.x;
    const int e0 = blockIdx.x * BIN_CHUNK;
    const int cnt = min(BIN_CHUNK, E - e0);

    if (tid < nbuckets) bcnt[tid] = 0;
    __syncthreads();

    for (int i = tid; i < cnt; i += 256) {
        int s = src[e0 + i], d = dst[e0 + i];
        spair[i] = make_uint2((unsigned)s, (unsigned)d);
        atomicAdd(&bcnt[d >> NBUCKET_SHIFT], 1);
    }
    __syncthreads();

    if (tid < nbuckets) {
        int c = bcnt[tid];
        bbase[tid] = (c > 0) ? atomicAdd(&bcur[tid], c) : 0;
        bcnt[tid] = 0;   // reuse as local cursor
    }
    __syncthreads();

    for (int i = tid; i < cnt; i += 256) {
        uint2 p = spair[i];
        int b = (int)(p.y >> NBUCKET_SHIFT);
        int off = atomicAdd(&bcnt[b], 1);
        pairs[bbase[b] + off] = p;
    }
}

// ---------------- phase 4: per-bucket rowptr + dinv + colsrc ------------------
__global__ __launch_bounds__(256)
void bucket_build_kernel(const int* __restrict__ bktbase, const uint2* __restrict__ pairs,
                         int* __restrict__ rowptr, float* __restrict__ dinv,
                         int* __restrict__ colsrc, int N) {
    __shared__ int cnt[256];
    __shared__ int sm[256];
    const int tid = threadIdx.x;
    const int nb0 = blockIdx.x << NBUCKET_SHIFT;
    const int lo = bktbase[blockIdx.x], hi = bktbase[blockIdx.x + 1];

    cnt[tid] = 0;
    __syncthreads();
    for (int i = lo + tid; i < hi; i += 256)
        atomicAdd(&cnt[(int)pairs[i].y - nb0], 1);
    __syncthreads();

    int v = cnt[tid];
    sm[tid] = v;
    __syncthreads();
#pragma unroll
    for (int off = 1; off < 256; off <<= 1) {
        int u = (tid >= off) ? sm[tid - off] : 0;
        __syncthreads();
        sm[tid] += u;
        __syncthreads();
    }
    int excl = sm[tid] - v;
    int node = nb0 + tid;
    if (node < N) {
        rowptr[node] = lo + excl;
        dinv[node] = rsqrtf((float)v + 1.0f);   // +1 self-loop
    }
    __syncthreads();
    cnt[tid] = lo + excl;   // reuse as scatter cursor
    __syncthreads();
    for (int i = lo + tid; i < hi; i += 256) {
        uint2 p = pairs[i];
        int pos = atomicAdd(&cnt[(int)p.y - nb0], 1);
        colsrc[pos] = (int)p.x;
    }
}

// ---------------- W1 -> Wt[n][k] bf16 pack (16K elems, one-shot) --------------
__global__ __launch_bounds__(256)
void wt_kernel(const float* __restrict__ W, unsigned short* __restrict__ wt) {
    int idx = blockIdx.x * 256 + threadIdx.x;    // 0..16383
    int n = idx & 127, k = idx >> 7;
    // read coalesced over n; write strided (tiny array, L2 absorbs)
    wt[n * 128 + k] = pack_bf16(W[k * 128 + n]);
}

// ---------------- gemm1: MFMA bf16, hi/lo split-A ----------------
// Block = 4 waves, 64 rows. Wave = 16 rows x 128 cols: 8 col-tiles x 4 k-steps,
// 2 MFMA (hi+lo) each. A loaded from global fp32 (line-exact), B from Wt (L1-hot).
// Epilogue: per-wave LDS transpose (stride 132 -> 2-way bank aliasing, free),
// dinv scale + bf16 pack, slice-major h1b with fully-coalesced 1 KB stores.
__global__ __launch_bounds__(256)
void gemm1_mfma_kernel(const float* __restrict__ x, const unsigned short* __restrict__ wt,
                       const float* __restrict__ dinv, unsigned* __restrict__ h1b, int N) {
    __shared__ float lds[4][16 * 132];   // 33792 B
    const int tid = threadIdx.x, wave = tid >> 6, lane = tid & 63;
    const int q = lane >> 4, m = lane & 15;
    const int row0 = blockIdx.x * 64 + wave * 16;
    const int row = row0 + m;
    const int rowc = (row < N) ? row : (N - 1);   // clamp (OOB rows masked at store)

    f32x4 acc[8];
#pragma unroll
    for (int t = 0; t < 8; t++) acc[t] = (f32x4)0.0f;

#pragma unroll
    for (int ks = 0; ks < 4; ks++) {
        // A fragment: x[row][ks*32 + q*8 .. +7], fp32 -> bf16 hi/lo
        const float4* xp = (const float4*)(x + (size_t)rowc * 128 + ks * 32 + q * 8);
        float4 f0 = xp[0], f1 = xp[1];
        float fv[8] = {f0.x, f0.y, f0.z, f0.w, f1.x, f1.y, f1.z, f1.w};
        bf16x8 ah, al;
#pragma unroll
        for (int j = 0; j < 8; j++) {
            __bf16 h = (__bf16)fv[j];
            ah[j] = h;
            al[j] = (__bf16)(fv[j] - (float)h);
        }
#pragma unroll
        for (int t = 0; t < 8; t++) {
            // B fragment: Wt[n = t*16+m][ks*32 + q*8 .. +7]
            bf16x8 b = *(const bf16x8*)(wt + (size_t)(t * 16 + m) * 128 + ks * 32 + q * 8);
            acc[t] = __builtin_amdgcn_mfma_f32_16x16x32_bf16(ah, b, acc[t], 0, 0, 0);
            acc[t] = __builtin_amdgcn_mfma_f32_16x16x32_bf16(al, b, acc[t], 0, 0, 0);
        }
    }

    // D layout: col = m, row = q*4 + r. Scatter into per-wave LDS tile.
#pragma unroll
    for (int t = 0; t < 8; t++)
#pragma unroll
        for (int r = 0; r < 4; r++)
            lds[wave][(q * 4 + r) * 132 + t * 16 + m] = acc[t][r];
    __syncthreads();

    // Pack + store: lane = (row within 16)*4 + 16B-chunk j -> contiguous 1 KB/slice.
    const int r2 = lane >> 2, j = lane & 3;
    const int orow = row0 + r2;
    if (orow < N) {
        float dv = dinv[orow];
        const float* lrow = &lds[wave][r2 * 132];
#pragma unroll
        for (int s = 0; s < 4; s++) {
            float4 a = *(const float4*)(lrow + s * 32 + j * 8);
            float4 b = *(const float4*)(lrow + s * 32 + j * 8 + 4);
            uint4 p;
            p.x = pack_bf16x2(a.x * dv, a.y * dv);
            p.y = pack_bf16x2(a.z * dv, a.w * dv);
            p.z = pack_bf16x2(b.x * dv, b.y * dv);
            p.w = pack_bf16x2(b.z * dv, b.w * dv);
            ((uint4*)(h1b + (size_t)s * N * 16))[(size_t)orow * 4 + j] = p;
        }
    }
}

// ---------------- layer-1 pull, one 32-feature slice ----------------
__global__ __launch_bounds__(256)
void l1_pass_kernel(const int* __restrict__ rowptr, const int* __restrict__ colsrc,
                    const unsigned* __restrict__ h1b_s, float* __restrict__ agg_s, int N) {
    const int tid = threadIdx.x;
    const int wave = tid >> 6, lane = tid & 63;
    const int n = lane >> 4;          // node 0..3 within wave
    const int g = (lane >> 2) & 3;    // edge group 0..3
    const int c = lane & 3;           // uint4 chunk 0..3
    const int d = blockIdx.x * 16 + wave * 4 + n;
    if (d >= N) return;
    const uint4* hq = (const uint4*)h1b_s;   // node row = 4 uint4

    float a[8];
#pragma unroll
    for (int j = 0; j < 8; j++) a[j] = 0.0f;

    if (g == 0) {                     // self-loop term
        uint4 v = hq[(size_t)d * 4 + c];
        float2 t;
        t = unpack_bf16x2(v.x); a[0] += t.x; a[1] += t.y;
        t = unpack_bf16x2(v.y); a[2] += t.x; a[3] += t.y;
        t = unpack_bf16x2(v.z); a[4] += t.x; a[5] += t.y;
        t = unpack_bf16x2(v.w); a[6] += t.x; a[7] += t.y;
    }

    int i = rowptr[d], end = rowptr[d + 1];
    for (; i + 8 <= end; i += 8) {    // 8 edges, 2 gathers in flight
        int sA = colsrc[i + g], sB = colsrc[i + 4 + g];
        uint4 vA = hq[(size_t)sA * 4 + c];
        uint4 vB = hq[(size_t)sB * 4 + c];
        float2 t;
        t = unpack_bf16x2(vA.x); a[0] += t.x; a[1] += t.y;
        t = unpack_bf16x2(vA.y); a[2] += t.x; a[3] += t.y;
        t = unpack_bf16x2(vA.z); a[4] += t.x; a[5] += t.y;
        t = unpack_bf16x2(vA.w); a[6] += t.x; a[7] += t.y;
        t = unpack_bf16x2(vB.x); a[0] += t.x; a[1] += t.y;
        t = unpack_bf16x2(vB.y); a[2] += t.x; a[3] += t.y;
        t = unpack_bf16x2(vB.z); a[4] += t.x; a[5] += t.y;
        t = unpack_bf16x2(vB.w); a[6] += t.x; a[7] += t.y;
    }
    for (; i + 4 <= end; i += 4) {
        int sx = colsrc[i + g];
        uint4 v = hq[(size_t)sx * 4 + c];
        float2 t;
        t = unpack_bf16x2(v.x); a[0] += t.x; a[1] += t.y;
        t = unpack_bf16x2(v.y); a[2] += t.x; a[3] += t.y;
        t = unpack_bf16x2(v.z); a[4] += t.x; a[5] += t.y;
        t = unpack_bf16x2(v.w); a[6] += t.x; a[7] += t.y;
    }
    if (i < end && g < end - i) {     // tail (<4 edges)
        int sx = colsrc[i + g];
        uint4 v = hq[(size_t)sx * 4 + c];
        float2 t;
        t = unpack_bf16x2(v.x); a[0] += t.x; a[1] += t.y;
        t = unpack_bf16x2(v.y); a[2] += t.x; a[3] += t.y;
        t = unpack_bf16x2(v.z); a[4] += t.x; a[5] += t.y;
        t = unpack_bf16x2(v.w); a[6] += t.x; a[7] += t.y;
    }

#pragma unroll
    for (int j = 0; j < 8; j++) {     // combine 4 edge groups (within 16-lane node)
        a[j] += __shfl_xor(a[j], 4, 64);
        a[j] += __shfl_xor(a[j], 8, 64);
    }
    if (g == 0) {
        ((float4*)agg_s)[(size_t)d * 8 + c * 2] = make_float4(a[0], a[1], a[2], a[3]);
        ((float4*)agg_s)[(size_t)d * 8 + c * 2 + 1] = make_float4(a[4], a[5], a[6], a[7]);
    }
}

// ---------------- gemm2: h2s[N,16] = dinv * (relu(dinv*agg + b1) @ W2) --------
__global__ __launch_bounds__(256)
void gemm2_kernel(const float* __restrict__ agg, const float* __restrict__ dinv,
                  const float* __restrict__ b1, const float* __restrict__ W2,
                  float* __restrict__ h2s, int N) {
    __shared__ float hs[16 * 128];
    __shared__ float w2s[128 * 16];
    const int tid = threadIdx.x;
    const int row0 = blockIdx.x * 16;

    for (int i = tid; i < 512; i += 256)
        ((float4*)w2s)[i] = ((const float4*)W2)[i];

    for (int i = tid; i < 512; i += 256) {
        int r = i >> 5, q = i & 31;           // q = float4 index within 128-col row
        int row = row0 + r;
        float4 v = make_float4(0.f, 0.f, 0.f, 0.f);
        if (row < N) {
            int s = q >> 3, qq = q & 7;
            v = ((const float4*)agg)[(size_t)s * N * 8 + (size_t)row * 8 + qq];
            float dv = dinv[row];
            float4 b = ((const float4*)b1)[q];
            v.x = fmaxf(v.x * dv + b.x, 0.f);
            v.y = fmaxf(v.y * dv + b.y, 0.f);
            v.z = fmaxf(v.z * dv + b.z, 0.f);
            v.w = fmaxf(v.w * dv + b.w, 0.f);
        }
        ((float4*)hs)[i] = v;
    }
    __syncthreads();

    int r = tid >> 4, c = tid & 15;
    float acc = 0.0f;
#pragma unroll 16
    for (int k = 0; k < 128; k++)
        acc = fmaf(hs[r * 128 + k], w2s[k * 16 + c], acc);

    int row = row0 + r;
    if (row < N) h2s[row * 16 + c] = acc * dinv[row];   // pre-scale for layer 2
}

// ---------------- fused layer-2 pull + log_softmax ----------------
__global__ __launch_bounds__(256)
void l2_kernel(const int* __restrict__ rowptr, const int* __restrict__ colsrc,
               const float* __restrict__ dinv, const float* __restrict__ h2s,
               const float* __restrict__ b2, float* __restrict__ out, int N) {
    const int tid = threadIdx.x;
    const int wave = tid >> 6, lane = tid & 63;
    const int g = lane >> 2;          // edge group 0..15
    const int c = lane & 3;           // float4 chunk (4 feats)
    const int d = blockIdx.x * 4 + wave;
    if (d >= N) return;
    const float4* h2q = (const float4*)h2s;  // row = 4 float4

    float4 acc = make_float4(0.f, 0.f, 0.f, 0.f);
    if (g == 0) acc = h2q[d * 4 + c];        // self-loop term
    int i = rowptr[d], end = rowptr[d + 1];
    for (; i + 16 <= end; i += 16) {
        int s = colsrc[i + g];
        float4 v = h2q[s * 4 + c];
        acc.x += v.x; acc.y += v.y; acc.z += v.z; acc.w += v.w;
    }
    if (i < end && g < end - i) {            // tail (<16 edges)
        int s = colsrc[i + g];
        float4 v = h2q[s * 4 + c];
        acc.x += v.x; acc.y += v.y; acc.z += v.z; acc.w += v.w;
    }
#pragma unroll
    for (int off = 4; off <= 32; off <<= 1) {
        acc.x += __shfl_xor(acc.x, off, 64);
        acc.y += __shfl_xor(acc.y, off, 64);
        acc.z += __shfl_xor(acc.z, off, 64);
        acc.w += __shfl_xor(acc.w, off, 64);
    }
    float dv = dinv[d];
    float4 b = ((const float4*)b2)[c];
    float4 val = make_float4(acc.x * dv + b.x, acc.y * dv + b.y,
                             acc.z * dv + b.z, acc.w * dv + b.w);
    float m = fmaxf(fmaxf(val.x, val.y), fmaxf(val.z, val.w));
    m = fmaxf(m, __shfl_xor(m, 1, 64));
    m = fmaxf(m, __shfl_xor(m, 2, 64));
    float e = expf(val.x - m) + expf(val.y - m) + expf(val.z - m) + expf(val.w - m);
    e += __shfl_xor(e, 1, 64);
    e += __shfl_xor(e, 2, 64);
    float lse = m + logf(e);
    if (g == 0)
        ((float4*)out)[d * 4 + c] =
            make_float4(val.x - lse, val.y - lse, val.z - lse, val.w - lse);
}

extern "C" void kernel_launch(void* const* d_in, const int* in_sizes, int n_in,
                              void* d_out, int out_size, void* d_ws, size_t ws_size,
                              hipStream_t stream) {
    const float* x  = (const float*)d_in[0];
    const int*  ei  = (const int*)d_in[1];
    const float* W1 = (const float*)d_in[2];
    const float* b1 = (const float*)d_in[3];
    const float* W2 = (const float*)d_in[4];
    const float* b2 = (const float*)d_in[5];
    float* out = (float*)d_out;

    const int N = in_sizes[0] / 128;   // 50000
    const int E = in_sizes[1] / 2;     // 800000
    const int* src = ei;
    const int* dst = ei + E;
    const int nbuckets = (N + 255) >> NBUCKET_SHIFT;   // 196 (< 256 required)
    const int nbins = (E + BIN_CHUNK - 1) / BIN_CHUNK; // 196

    // Workspace layout (4B units; prefix stays 16B-aligned):
    //   dinv    : N floats
    //   rowptr  : N+4 ints
    //   bktcnt  : 256 ints
    //   bktbase : 260 ints
    //   bcur    : 256 ints
    //   wt      : 128*128 bf16 = 8192 uints-worth (32 KB)
    //   colsrc  : E ints (3.2 MB)
    //   pairs   : E uint2 (6.4 MB)  -- dead after bucket_build; agg overlays it
    //   agg     : N*128 floats (25.6 MB, slice-major 4 x N*32) at pairs base
    //   h1b     : N*64 uints (12.8 MB, slice-major 4 x N*16)
    //   h2s     : N*16 floats (3.2 MB)        peak ~45 MB
    float*          wsf     = (float*)d_ws;
    float*          dinv    = wsf;
    int*            rowptr  = (int*)(wsf + N);
    int*            bktcnt  = rowptr + N + 4;
    int*            bktbase = bktcnt + 256;
    int*            bcur    = bktbase + 260;
    unsigned short* wt      = (unsigned short*)(bcur + 256);
    int*            colsrc  = bcur + 256 + 8192;
    uint2*          pairs   = (uint2*)(colsrc + E);
    float*          agg     = (float*)pairs;                    // overlays pairs
    unsigned*       h1b     = (unsigned*)(agg + (size_t)N * 128);
    float*          h2s     = (float*)(h1b + (size_t)N * 64);

    // ---- CSR build ----
    hipMemsetAsync(bktcnt, 0, 256 * sizeof(int), stream);
    bucket_count_kernel<<<nbins, 256, 0, stream>>>(dst, bktcnt, E, nbuckets);
    bucket_scan_kernel<<<1, 256, 0, stream>>>(bktcnt, bktbase, bcur, rowptr + N,
                                              nbuckets, E);
    bin_kernel<<<nbins, 256, 0, stream>>>(src, dst, bcur, pairs, E, nbuckets);
    bucket_build_kernel<<<nbuckets, 256, 0, stream>>>(bktbase, pairs, rowptr,
                                                      dinv, colsrc, N);

    // ---- layer 1 feature transform: Wt pack + MFMA gemm1 ----
    wt_kernel<<<64, 256, 0, stream>>>(W1, wt);
    gemm1_mfma_kernel<<<(N + 63) / 64, 256, 0, stream>>>(x, wt, dinv, h1b, N);

    // ---- layer-1 pull, 4 L2-resident slice passes (pairs now dead -> agg) ----
    {
        int blocks = (N + 15) / 16;
        for (int s = 0; s < 4; s++)
            l1_pass_kernel<<<blocks, 256, 0, stream>>>(
                rowptr, colsrc, h1b + (size_t)s * N * 16, agg + (size_t)s * N * 32, N);
    }

    // ---- gemm2 (+bias/relu, pre-scale) ----
    gemm2_kernel<<<(N + 15) / 16, 256, 0, stream>>>(agg, dinv, b1, W2, h2s, N);

    // ---- fused pull-aggregation 2 + bias + log_softmax ----
    l2_kernel<<<(N + 3) / 4, 256, 0, stream>>>(rowptr, colsrc, dinv, h2s, b2, out, N);
}

// Round 9
// 219.046 us; speedup vs baseline: 4.2321x; 1.0456x over previous
//
#include <hip/hip_runtime.h>
#include <math.h>

// GCN, N=50000 nodes, E=800000 edges, F_IN=128, H=128, C=16. f32 in/out; edges int32.
//
// R2: CSR-by-dst pull aggregation (no float atomics), dinv pre-scaling.
// R3: multi-block scan. R4: bf16 h1 staging. R5: counting-sort CSR build.
// R6: vectorized gathers. R7: 4 L2-resident feature-slice passes for l1.
// R8: gemm1 -> MFMA 16x16x32 bf16 with hi/lo split-A.
// R9: W1 pre-swizzled into MFMA fragment order (wtp[(t*4+ks)*64 + lane] x 16B):
//     B-fragment loads become one coalesced 1 KB wave-load instead of a 64-lane
//     scatter over 16 cache lines (the R8 gemm1 was still ~30 us on B gathers).

#define NBUCKET_SHIFT 8                   // bucket = dst >> 8 (256 nodes/bucket)
#define BIN_CHUNK 4096                    // edges per binning block

typedef __bf16 bf16x8 __attribute__((ext_vector_type(8)));
typedef float  f32x4  __attribute__((ext_vector_type(4)));

__device__ __forceinline__ unsigned short pack_bf16(float f) {
    unsigned u = __float_as_uint(f);
    return (unsigned short)((u + 0x7fffu + ((u >> 16) & 1u)) >> 16);   // RNE
}

__device__ __forceinline__ unsigned pack_bf16x2(float a, float b) {
    return ((unsigned)pack_bf16(b) << 16) | pack_bf16(a);
}

__device__ __forceinline__ float2 unpack_bf16x2(unsigned u) {
    return make_float2(__uint_as_float(u << 16), __uint_as_float(u & 0xffff0000u));
}

// ---------------- CSR build phase 1: per-bucket edge counts (LDS-staged) ------
__global__ __launch_bounds__(256)
void bucket_count_kernel(const int* __restrict__ dst, int* __restrict__ bktcnt,
                         int E, int nbuckets) {
    __shared__ int cnt[256];
    const int tid = threadIdx.x;
    cnt[tid] = 0;
    __syncthreads();
    const int e0 = blockIdx.x * BIN_CHUNK;
    const int n = min(BIN_CHUNK, E - e0);
    for (int i = tid; i < n; i += 256)
        atomicAdd(&cnt[dst[e0 + i] >> NBUCKET_SHIFT], 1);
    __syncthreads();
    if (tid < nbuckets && cnt[tid] > 0) atomicAdd(&bktcnt[tid], cnt[tid]);
}

// ---------------- phase 2: scan bucket counts -> bktbase, seed bin cursors ----
__global__ __launch_bounds__(256)
void bucket_scan_kernel(const int* __restrict__ bktcnt, int* __restrict__ bktbase,
                        int* __restrict__ bcur, int* __restrict__ rowptrN,
                        int nbuckets, int E) {
    __shared__ int sm[256];
    const int t = threadIdx.x;
    int v = (t < nbuckets) ? bktcnt[t] : 0;
    sm[t] = v;
    __syncthreads();
#pragma unroll
    for (int off = 1; off < 256; off <<= 1) {
        int u = (t >= off) ? sm[t - off] : 0;
        __syncthreads();
        sm[t] += u;
        __syncthreads();
    }
    int excl = sm[t] - v;
    if (t < nbuckets) { bktbase[t] = excl; bcur[t] = excl; }
    if (t == nbuckets - 1) bktbase[nbuckets] = excl + v;   // == E
    if (t == 0) *rowptrN = E;
}

// ---------------- phase 3: bin edges into bucket-major pair array -------------
__global__ __launch_bounds__(256)
void bin_kernel(const int* __restrict__ src, const int* __restrict__ dst,
                int* __restrict__ bcur, uint2* __restrict__ pairs, int E, int nbuckets) {
    __shared__ uint2 spair[BIN_CHUNK];   // 32 KB
    __shared__ int bcnt[256];
    __shared__ int bbase[256];
    const int tid = threadIdx.x;
    const int e0 = blockIdx.x * BIN_CHUNK;
    const int cnt = min(BIN_CHUNK, E - e0);

    if (tid < nbuckets) bcnt[tid] = 0;
    __syncthreads();

    for (int i = tid; i < cnt; i += 256) {
        int s = src[e0 + i], d = dst[e0 + i];
        spair[i] = make_uint2((unsigned)s, (unsigned)d);
        atomicAdd(&bcnt[d >> NBUCKET_SHIFT], 1);
    }
    __syncthreads();

    if (tid < nbuckets) {
        int c = bcnt[tid];
        bbase[tid] = (c > 0) ? atomicAdd(&bcur[tid], c) : 0;
        bcnt[tid] = 0;   // reuse as local cursor
    }
    __syncthreads();

    for (int i = tid; i < cnt; i += 256) {
        uint2 p = spair[i];
        int b = (int)(p.y >> NBUCKET_SHIFT);
        int off = atomicAdd(&bcnt[b], 1);
        pairs[bbase[b] + off] = p;
    }
}

// ---------------- phase 4: per-bucket rowptr + dinv + colsrc ------------------
__global__ __launch_bounds__(256)
void bucket_build_kernel(const int* __restrict__ bktbase, const uint2* __restrict__ pairs,
                         int* __restrict__ rowptr, float* __restrict__ dinv,
                         int* __restrict__ colsrc, int N) {
    __shared__ int cnt[256];
    __shared__ int sm[256];
    const int tid = threadIdx.x;
    const int nb0 = blockIdx.x << NBUCKET_SHIFT;
    const int lo = bktbase[blockIdx.x], hi = bktbase[blockIdx.x + 1];

    cnt[tid] = 0;
    __syncthreads();
    for (int i = lo + tid; i < hi; i += 256)
        atomicAdd(&cnt[(int)pairs[i].y - nb0], 1);
    __syncthreads();

    int v = cnt[tid];
    sm[tid] = v;
    __syncthreads();
#pragma unroll
    for (int off = 1; off < 256; off <<= 1) {
        int u = (tid >= off) ? sm[tid - off] : 0;
        __syncthreads();
        sm[tid] += u;
        __syncthreads();
    }
    int excl = sm[tid] - v;
    int node = nb0 + tid;
    if (node < N) {
        rowptr[node] = lo + excl;
        dinv[node] = rsqrtf((float)v + 1.0f);   // +1 self-loop
    }
    __syncthreads();
    cnt[tid] = lo + excl;   // reuse as scatter cursor
    __syncthreads();
    for (int i = lo + tid; i < hi; i += 256) {
        uint2 p = pairs[i];
        int pos = atomicAdd(&cnt[(int)p.y - nb0], 1);
        colsrc[pos] = (int)p.x;
    }
}

// ---------------- W1 -> MFMA-fragment-order bf16 pack (one-shot) --------------
// wtp layout: for tile t (cols t*16..+15) and k-step ks (k = ks*32..+31):
//   frag base = (t*4+ks)*512 shorts; lane (q=lane>>4, m=lane&15) owns 8 shorts
//   at base + lane*8 + j  =  Wt[n=t*16+m][k=ks*32+q*8+j] = W1[k][n].
__global__ __launch_bounds__(256)
void wt_kernel(const float* __restrict__ W, unsigned short* __restrict__ wtp) {
    int idx = blockIdx.x * 256 + threadIdx.x;    // 0..16383
    int j    = idx & 7;
    int lane = (idx >> 3) & 63;
    int ks   = (idx >> 9) & 3;
    int t    = idx >> 11;
    int n = t * 16 + (lane & 15);
    int k = ks * 32 + ((lane >> 4) << 3) + j;
    wtp[idx] = pack_bf16(W[k * 128 + n]);
}

// ---------------- gemm1: MFMA bf16, hi/lo split-A ----------------
// Block = 4 waves, 64 rows. Wave = 16 rows x 128 cols: 8 col-tiles x 4 k-steps,
// 2 MFMA (hi+lo) each. A from global fp32; B via one coalesced 1 KB wave-load
// per (t,ks) from the fragment-ordered wtp (32 KB, L1-hot).
// Epilogue: per-wave LDS transpose (stride 132), dinv scale + bf16 pack,
// slice-major h1b with fully-coalesced stores.
__global__ __launch_bounds__(256)
void gemm1_mfma_kernel(const float* __restrict__ x, const unsigned short* __restrict__ wtp,
                       const float* __restrict__ dinv, unsigned* __restrict__ h1b, int N) {
    __shared__ float lds[4][16 * 132];   // 33792 B
    const int tid = threadIdx.x, wave = tid >> 6, lane = tid & 63;
    const int q = lane >> 4, m = lane & 15;
    const int row0 = blockIdx.x * 64 + wave * 16;
    const int row = row0 + m;
    const int rowc = (row < N) ? row : (N - 1);   // clamp (OOB rows masked at store)

    f32x4 acc[8];
#pragma unroll
    for (int t = 0; t < 8; t++) acc[t] = (f32x4)0.0f;

#pragma unroll
    for (int ks = 0; ks < 4; ks++) {
        // A fragment: x[row][ks*32 + q*8 .. +7], fp32 -> bf16 hi/lo
        const float4* xp = (const float4*)(x + (size_t)rowc * 128 + ks * 32 + q * 8);
        float4 f0 = xp[0], f1 = xp[1];
        float fv[8] = {f0.x, f0.y, f0.z, f0.w, f1.x, f1.y, f1.z, f1.w};
        bf16x8 ah, al;
#pragma unroll
        for (int j = 0; j < 8; j++) {
            __bf16 h = (__bf16)fv[j];
            ah[j] = h;
            al[j] = (__bf16)(fv[j] - (float)h);
        }
#pragma unroll
        for (int t = 0; t < 8; t++) {
            bf16x8 b = *(const bf16x8*)(wtp + (size_t)(t * 4 + ks) * 512 + lane * 8);
            acc[t] = __builtin_amdgcn_mfma_f32_16x16x32_bf16(ah, b, acc[t], 0, 0, 0);
            acc[t] = __builtin_amdgcn_mfma_f32_16x16x32_bf16(al, b, acc[t], 0, 0, 0);
        }
    }

    // D layout: col = m, row = q*4 + r. Scatter into per-wave LDS tile.
#pragma unroll
    for (int t = 0; t < 8; t++)
#pragma unroll
        for (int r = 0; r < 4; r++)
            lds[wave][(q * 4 + r) * 132 + t * 16 + m] = acc[t][r];
    __syncthreads();

    // Pack + store: lane = (row within 16)*4 + 16B-chunk j -> contiguous 1 KB/slice.
    const int r2 = lane >> 2, j = lane & 3;
    const int orow = row0 + r2;
    if (orow < N) {
        float dv = dinv[orow];
        const float* lrow = &lds[wave][r2 * 132];
#pragma unroll
        for (int s = 0; s < 4; s++) {
            float4 a = *(const float4*)(lrow + s * 32 + j * 8);
            float4 b = *(const float4*)(lrow + s * 32 + j * 8 + 4);
            uint4 p;
            p.x = pack_bf16x2(a.x * dv, a.y * dv);
            p.y = pack_bf16x2(a.z * dv, a.w * dv);
            p.z = pack_bf16x2(b.x * dv, b.y * dv);
            p.w = pack_bf16x2(b.z * dv, b.w * dv);
            ((uint4*)(h1b + (size_t)s * N * 16))[(size_t)orow * 4 + j] = p;
        }
    }
}

// ---------------- layer-1 pull, one 32-feature slice ----------------
__global__ __launch_bounds__(256)
void l1_pass_kernel(const int* __restrict__ rowptr, const int* __restrict__ colsrc,
                    const unsigned* __restrict__ h1b_s, float* __restrict__ agg_s, int N) {
    const int tid = threadIdx.x;
    const int wave = tid >> 6, lane = tid & 63;
    const int n = lane >> 4;          // node 0..3 within wave
    const int g = (lane >> 2) & 3;    // edge group 0..3
    const int c = lane & 3;           // uint4 chunk 0..3
    const int d = blockIdx.x * 16 + wave * 4 + n;
    if (d >= N) return;
    const uint4* hq = (const uint4*)h1b_s;   // node row = 4 uint4

    float a[8];
#pragma unroll
    for (int j = 0; j < 8; j++) a[j] = 0.0f;

    if (g == 0) {                     // self-loop term
        uint4 v = hq[(size_t)d * 4 + c];
        float2 t;
        t = unpack_bf16x2(v.x); a[0] += t.x; a[1] += t.y;
        t = unpack_bf16x2(v.y); a[2] += t.x; a[3] += t.y;
        t = unpack_bf16x2(v.z); a[4] += t.x; a[5] += t.y;
        t = unpack_bf16x2(v.w); a[6] += t.x; a[7] += t.y;
    }

    int i = rowptr[d], end = rowptr[d + 1];
    for (; i + 8 <= end; i += 8) {    // 8 edges, 2 gathers in flight
        int sA = colsrc[i + g], sB = colsrc[i + 4 + g];
        uint4 vA = hq[(size_t)sA * 4 + c];
        uint4 vB = hq[(size_t)sB * 4 + c];
        float2 t;
        t = unpack_bf16x2(vA.x); a[0] += t.x; a[1] += t.y;
        t = unpack_bf16x2(vA.y); a[2] += t.x; a[3] += t.y;
        t = unpack_bf16x2(vA.z); a[4] += t.x; a[5] += t.y;
        t = unpack_bf16x2(vA.w); a[6] += t.x; a[7] += t.y;
        t = unpack_bf16x2(vB.x); a[0] += t.x; a[1] += t.y;
        t = unpack_bf16x2(vB.y); a[2] += t.x; a[3] += t.y;
        t = unpack_bf16x2(vB.z); a[4] += t.x; a[5] += t.y;
        t = unpack_bf16x2(vB.w); a[6] += t.x; a[7] += t.y;
    }
    for (; i + 4 <= end; i += 4) {
        int sx = colsrc[i + g];
        uint4 v = hq[(size_t)sx * 4 + c];
        float2 t;
        t = unpack_bf16x2(v.x); a[0] += t.x; a[1] += t.y;
        t = unpack_bf16x2(v.y); a[2] += t.x; a[3] += t.y;
        t = unpack_bf16x2(v.z); a[4] += t.x; a[5] += t.y;
        t = unpack_bf16x2(v.w); a[6] += t.x; a[7] += t.y;
    }
    if (i < end && g < end - i) {     // tail (<4 edges)
        int sx = colsrc[i + g];
        uint4 v = hq[(size_t)sx * 4 + c];
        float2 t;
        t = unpack_bf16x2(v.x); a[0] += t.x; a[1] += t.y;
        t = unpack_bf16x2(v.y); a[2] += t.x; a[3] += t.y;
        t = unpack_bf16x2(v.z); a[4] += t.x; a[5] += t.y;
        t = unpack_bf16x2(v.w); a[6] += t.x; a[7] += t.y;
    }

#pragma unroll
    for (int j = 0; j < 8; j++) {     // combine 4 edge groups (within 16-lane node)
        a[j] += __shfl_xor(a[j], 4, 64);
        a[j] += __shfl_xor(a[j], 8, 64);
    }
    if (g == 0) {
        ((float4*)agg_s)[(size_t)d * 8 + c * 2] = make_float4(a[0], a[1], a[2], a[3]);
        ((float4*)agg_s)[(size_t)d * 8 + c * 2 + 1] = make_float4(a[4], a[5], a[6], a[7]);
    }
}

// ---------------- gemm2: h2s[N,16] = dinv * (relu(dinv*agg + b1) @ W2) --------
__global__ __launch_bounds__(256)
void gemm2_kernel(const float* __restrict__ agg, const float* __restrict__ dinv,
                  const float* __restrict__ b1, const float* __restrict__ W2,
                  float* __restrict__ h2s, int N) {
    __shared__ float hs[16 * 128];
    __shared__ float w2s[128 * 16];
    const int tid = threadIdx.x;
    const int row0 = blockIdx.x * 16;

    for (int i = tid; i < 512; i += 256)
        ((float4*)w2s)[i] = ((const float4*)W2)[i];

    for (int i = tid; i < 512; i += 256) {
        int r = i >> 5, q = i & 31;           // q = float4 index within 128-col row
        int row = row0 + r;
        float4 v = make_float4(0.f, 0.f, 0.f, 0.f);
        if (row < N) {
            int s = q >> 3, qq = q & 7;
            v = ((const float4*)agg)[(size_t)s * N * 8 + (size_t)row * 8 + qq];
            float dv = dinv[row];
            float4 b = ((const float4*)b1)[q];
            v.x = fmaxf(v.x * dv + b.x, 0.f);
            v.y = fmaxf(v.y * dv + b.y, 0.f);
            v.z = fmaxf(v.z * dv + b.z, 0.f);
            v.w = fmaxf(v.w * dv + b.w, 0.f);
        }
        ((float4*)hs)[i] = v;
    }
    __syncthreads();

    int r = tid >> 4, c = tid & 15;
    float acc = 0.0f;
#pragma unroll 16
    for (int k = 0; k < 128; k++)
        acc = fmaf(hs[r * 128 + k], w2s[k * 16 + c], acc);

    int row = row0 + r;
    if (row < N) h2s[row * 16 + c] = acc * dinv[row];   // pre-scale for layer 2
}

// ---------------- fused layer-2 pull + log_softmax ----------------
__global__ __launch_bounds__(256)
void l2_kernel(const int* __restrict__ rowptr, const int* __restrict__ colsrc,
               const float* __restrict__ dinv, const float* __restrict__ h2s,
               const float* __restrict__ b2, float* __restrict__ out, int N) {
    const int tid = threadIdx.x;
    const int wave = tid >> 6, lane = tid & 63;
    const int g = lane >> 2;          // edge group 0..15
    const int c = lane & 3;           // float4 chunk (4 feats)
    const int d = blockIdx.x * 4 + wave;
    if (d >= N) return;
    const float4* h2q = (const float4*)h2s;  // row = 4 float4

    float4 acc = make_float4(0.f, 0.f, 0.f, 0.f);
    if (g == 0) acc = h2q[d * 4 + c];        // self-loop term
    int i = rowptr[d], end = rowptr[d + 1];
    for (; i + 16 <= end; i += 16) {
        int s = colsrc[i + g];
        float4 v = h2q[s * 4 + c];
        acc.x += v.x; acc.y += v.y; acc.z += v.z; acc.w += v.w;
    }
    if (i < end && g < end - i) {            // tail (<16 edges)
        int s = colsrc[i + g];
        float4 v = h2q[s * 4 + c];
        acc.x += v.x; acc.y += v.y; acc.z += v.z; acc.w += v.w;
    }
#pragma unroll
    for (int off = 4; off <= 32; off <<= 1) {
        acc.x += __shfl_xor(acc.x, off, 64);
        acc.y += __shfl_xor(acc.y, off, 64);
        acc.z += __shfl_xor(acc.z, off, 64);
        acc.w += __shfl_xor(acc.w, off, 64);
    }
    float dv = dinv[d];
    float4 b = ((const float4*)b2)[c];
    float4 val = make_float4(acc.x * dv + b.x, acc.y * dv + b.y,
                             acc.z * dv + b.z, acc.w * dv + b.w);
    float m = fmaxf(fmaxf(val.x, val.y), fmaxf(val.z, val.w));
    m = fmaxf(m, __shfl_xor(m, 1, 64));
    m = fmaxf(m, __shfl_xor(m, 2, 64));
    float e = expf(val.x - m) + expf(val.y - m) + expf(val.z - m) + expf(val.w - m);
    e += __shfl_xor(e, 1, 64);
    e += __shfl_xor(e, 2, 64);
    float lse = m + logf(e);
    if (g == 0)
        ((float4*)out)[d * 4 + c] =
            make_float4(val.x - lse, val.y - lse, val.z - lse, val.w - lse);
}

extern "C" void kernel_launch(void* const* d_in, const int* in_sizes, int n_in,
                              void* d_out, int out_size, void* d_ws, size_t ws_size,
                              hipStream_t stream) {
    const float* x  = (const float*)d_in[0];
    const int*  ei  = (const int*)d_in[1];
    const float* W1 = (const float*)d_in[2];
    const float* b1 = (const float*)d_in[3];
    const float* W2 = (const float*)d_in[4];
    const float* b2 = (const float*)d_in[5];
    float* out = (float*)d_out;

    const int N = in_sizes[0] / 128;   // 50000
    const int E = in_sizes[1] / 2;     // 800000
    const int* src = ei;
    const int* dst = ei + E;
    const int nbuckets = (N + 255) >> NBUCKET_SHIFT;   // 196 (< 256 required)
    const int nbins = (E + BIN_CHUNK - 1) / BIN_CHUNK; // 196

    // Workspace layout (4B units; prefix stays 16B-aligned):
    //   dinv    : N floats
    //   rowptr  : N+4 ints
    //   bktcnt  : 256 ints
    //   bktbase : 260 ints
    //   bcur    : 256 ints
    //   wtp     : 128*128 bf16 in MFMA fragment order (32 KB)
    //   colsrc  : E ints (3.2 MB)
    //   pairs   : E uint2 (6.4 MB)  -- dead after bucket_build; agg overlays it
    //   agg     : N*128 floats (25.6 MB, slice-major 4 x N*32) at pairs base
    //   h1b     : N*64 uints (12.8 MB, slice-major 4 x N*16)
    //   h2s     : N*16 floats (3.2 MB)        peak ~45 MB
    float*          wsf     = (float*)d_ws;
    float*          dinv    = wsf;
    int*            rowptr  = (int*)(wsf + N);
    int*            bktcnt  = rowptr + N + 4;
    int*            bktbase = bktcnt + 256;
    int*            bcur    = bktbase + 260;
    unsigned short* wtp     = (unsigned short*)(bcur + 256);
    int*            colsrc  = bcur + 256 + 8192;
    uint2*          pairs   = (uint2*)(colsrc + E);
    float*          agg     = (float*)pairs;                    // overlays pairs
    unsigned*       h1b     = (unsigned*)(agg + (size_t)N * 128);
    float*          h2s     = (float*)(h1b + (size_t)N * 64);

    // ---- CSR build ----
    hipMemsetAsync(bktcnt, 0, 256 * sizeof(int), stream);
    bucket_count_kernel<<<nbins, 256, 0, stream>>>(dst, bktcnt, E, nbuckets);
    bucket_scan_kernel<<<1, 256, 0, stream>>>(bktcnt, bktbase, bcur, rowptr + N,
                                              nbuckets, E);
    bin_kernel<<<nbins, 256, 0, stream>>>(src, dst, bcur, pairs, E, nbuckets);
    bucket_build_kernel<<<nbuckets, 256, 0, stream>>>(bktbase, pairs, rowptr,
                                                      dinv, colsrc, N);

    // ---- layer 1 feature transform: Wt fragment-pack + MFMA gemm1 ----
    wt_kernel<<<64, 256, 0, stream>>>(W1, wtp);
    gemm1_mfma_kernel<<<(N + 63) / 64, 256, 0, stream>>>(x, wtp, dinv, h1b, N);

    // ---- layer-1 pull, 4 L2-resident slice passes (pairs now dead -> agg) ----
    {
        int blocks = (N + 15) / 16;
        for (int s = 0; s < 4; s++)
            l1_pass_kernel<<<blocks, 256, 0, stream>>>(
                rowptr, colsrc, h1b + (size_t)s * N * 16, agg + (size_t)s * N * 32, N);
    }

    // ---- gemm2 (+bias/relu, pre-scale) ----
    gemm2_kernel<<<(N + 15) / 16, 256, 0, stream>>>(agg, dinv, b1, W2, h2s, N);

    // ---- fused pull-aggregation 2 + bias + log_softmax ----
    l2_kernel<<<(N + 3) / 4, 256, 0, stream>>>(rowptr, colsrc, dinv, h2s, b2, out, N);
}